// Round 9
// baseline (278.476 us; speedup 1.0000x reference)
//
#include <hip/hip_runtime.h>
#include <hip/hip_fp16.h>

#define D 64
#define CHUNK 4096
#define BSIZE 256          // nodes per bucket (dst >> 8)
#define NBUCKET 512        // covers up to 131072 nodes (src fits in 17 bits)

// ---- load/store helpers (fp32 or fp16 storage, fp32 compute) --------------
static __device__ __forceinline__ float ldf(const float* p)  { return *p; }
static __device__ __forceinline__ float ldf(const __half* p) { return __half2float(*p); }
static __device__ __forceinline__ void  stf(float* p, float v)  { *p = v; }
static __device__ __forceinline__ void  stf(__half* p, float v) { *p = __float2half(v); }

// ===========================================================================
// h = scale * (optional relu)(x) @ W^T   [n,64]x[64,64]; 32 nodes/block
// ===========================================================================
template <bool RELU, bool SCALE, typename IN_T, typename OUT_T>
__global__ void linear_kernel(const IN_T* __restrict__ x,
                              const float* __restrict__ W,
                              const float* __restrict__ dis,
                              OUT_T* __restrict__ h, int n) {
    __shared__ float sW[D * 65];
    __shared__ float sx[4][D];

    int t = threadIdx.x;
    #pragma unroll
    for (int j = 0; j < (D * D) / 256; ++j) {
        int idx = t + j * 256;
        int dd = idx >> 6, k = idx & 63;
        sW[dd * 65 + k] = W[idx];
    }

    int r = t >> 6, d = t & 63;
    int node0 = blockIdx.x * 32;
    for (int g = 0; g < 8; ++g) {
        int node = node0 + g * 4 + r;
        __syncthreads();                   // covers sW (g=0) and sx reuse
        float v = (node < n) ? ldf(&x[(size_t)node * D + d]) : 0.0f;
        if (RELU) v = fmaxf(v, 0.0f);
        sx[r][d] = v;
        __syncthreads();
        if (node < n) {
            float acc = 0.0f;
            #pragma unroll
            for (int k = 0; k < D; ++k)
                acc = fmaf(sx[r][k], sW[d * 65 + k], acc);
            if (SCALE) acc *= dis[node];
            stf(&h[(size_t)node * D + d], acc);
        }
    }
}

// ===========================================================================
// PARTITION PATH
// ===========================================================================
// A: per-chunk bucket histogram (LDS atomics only); 512 buckets, 256 threads
__global__ void part_hist_kernel(const int* __restrict__ dst, int e,
                                 int nchunk, int* __restrict__ hist) {
    __shared__ int cnt[NBUCKET];
    int t = threadIdx.x;
    cnt[t] = 0; cnt[t + 256] = 0;
    __syncthreads();
    int base = blockIdx.x * CHUNK;
    int end = min(base + CHUNK, e);
    int nv = (end - base) >> 2;
    for (int g = t; g < nv; g += 256) {
        int4 c4 = *(const int4*)(dst + base + g * 4);
        atomicAdd(&cnt[c4.x >> 8], 1);
        atomicAdd(&cnt[c4.y >> 8], 1);
        atomicAdd(&cnt[c4.z >> 8], 1);
        atomicAdd(&cnt[c4.w >> 8], 1);
    }
    if (t < ((end - base) & 3))
        atomicAdd(&cnt[dst[base + nv * 4 + t] >> 8], 1);
    __syncthreads();
    hist[(size_t)t * nchunk + blockIdx.x] = cnt[t];
    hist[(size_t)(t + 256) * nchunk + blockIdx.x] = cnt[t + 256];
}

// B1: per-bucket exclusive scan over its chunk counts (one block per bucket)
__global__ void part_scanA_kernel(const int* __restrict__ hist, int nchunk,
                                  int* __restrict__ ofs,
                                  int* __restrict__ btot) {
    __shared__ int sd[256];
    int b = blockIdx.x, t = threadIdx.x;
    int carry = 0;
    for (int base = 0; base < nchunk; base += 256) {
        int c = base + t;
        int v = (c < nchunk) ? hist[(size_t)b * nchunk + c] : 0;
        sd[t] = v;
        __syncthreads();
        for (int off = 1; off < 256; off <<= 1) {
            int x = (t >= off) ? sd[t - off] : 0;
            __syncthreads();
            sd[t] += x;
            __syncthreads();
        }
        if (c < nchunk) ofs[(size_t)b * nchunk + c] = carry + sd[t] - v;
        carry += sd[255];
        __syncthreads();
    }
    if (t == 0) btot[b] = carry;
}

// B2: scan NBUCKET totals -> bucketBase (single block of NBUCKET threads)
__global__ void part_scanB_kernel(const int* __restrict__ btot,
                                  int* __restrict__ bucketBase, int e) {
    __shared__ int sd[NBUCKET];
    int t = threadIdx.x;
    int v = btot[t];
    sd[t] = v;
    __syncthreads();
    for (int off = 1; off < NBUCKET; off <<= 1) {
        int x = (t >= off) ? sd[t - off] : 0;
        __syncthreads();
        sd[t] += x;
        __syncthreads();
    }
    bucketBase[t] = sd[t] - v;
    if (t == NBUCKET - 1) bucketBase[NBUCKET] = e;
}

// C: scatter edges into bucket-contiguous regions; pack (src | dlow<<17, ew)
__global__ void part_scatter_kernel(const int* __restrict__ src,
                                    const int* __restrict__ dst,
                                    const float* __restrict__ ew,
                                    const int* __restrict__ ofs,
                                    const int* __restrict__ bucketBase,
                                    int nchunk, int e,
                                    int2* __restrict__ psw) {
    __shared__ int cur[NBUCKET];
    int t = threadIdx.x;
    cur[t]       = bucketBase[t]       + ofs[(size_t)t * nchunk + blockIdx.x];
    cur[t + 256] = bucketBase[t + 256] + ofs[(size_t)(t + 256) * nchunk + blockIdx.x];
    __syncthreads();
    int base = blockIdx.x * CHUNK;
    int end = min(base + CHUNK, e);
    int nv = (end - base) >> 2;
    for (int g = t; g < nv; g += 256) {
        int i = base + g * 4;
        int4   c4 = *(const int4*)(dst + i);
        int4   s4 = *(const int4*)(src + i);
        float4 w4 = *(const float4*)(ew + i);
        int p0 = atomicAdd(&cur[c4.x >> 8], 1);
        int p1 = atomicAdd(&cur[c4.y >> 8], 1);
        int p2 = atomicAdd(&cur[c4.z >> 8], 1);
        int p3 = atomicAdd(&cur[c4.w >> 8], 1);
        psw[p0] = make_int2(s4.x | ((c4.x & 255) << 17), __float_as_int(w4.x));
        psw[p1] = make_int2(s4.y | ((c4.y & 255) << 17), __float_as_int(w4.y));
        psw[p2] = make_int2(s4.z | ((c4.z & 255) << 17), __float_as_int(w4.z));
        psw[p3] = make_int2(s4.w | ((c4.w & 255) << 17), __float_as_int(w4.w));
    }
    if (t < ((end - base) & 3)) {
        int k = base + nv * 4 + t;
        int c = dst[k];
        int p = atomicAdd(&cur[c >> 8], 1);
        psw[p] = make_int2(src[k] | ((c & 255) << 17), __float_as_int(ew[k]));
    }
}

// D: per-bucket binning -> CSR pairs (raw ew; no dis fold), row_ptr, dis
__global__ void bucket_bin_kernel(const int2* __restrict__ psw,
                                  const int* __restrict__ bucketBase,
                                  int n, int e,
                                  int2* __restrict__ pairs,
                                  int* __restrict__ row_ptr,
                                  float* __restrict__ dis) {
    __shared__ int   cnt[BSIZE];
    __shared__ float fdeg[BSIZE];
    __shared__ int   sc[BSIZE];

    int t = threadIdx.x;
    int b = blockIdx.x;
    int node0 = b * BSIZE;
    int ebeg = bucketBase[b], eend = bucketBase[b + 1];

    cnt[t] = 0;
    fdeg[t] = 0.0f;
    __syncthreads();

    // pass 1: node counts + weighted degree (LDS atomics)
    for (int i = ebeg + t; i < eend; i += 256) {
        int2 sw = psw[i];
        int c = sw.x >> 17;
        atomicAdd(&cnt[c], 1);
        atomicAdd(&fdeg[c], __int_as_float(sw.y));
    }
    __syncthreads();

    // exclusive scan of 256 counts
    int v = cnt[t];
    sc[t] = v;
    __syncthreads();
    for (int off = 1; off < 256; off <<= 1) {
        int x = (t >= off) ? sc[t - off] : 0;
        __syncthreads();
        sc[t] += x;
        __syncthreads();
    }
    int excl = sc[t] - v;

    int node = node0 + t;
    if (node < n) {
        row_ptr[node] = ebeg + excl;
        float dg = 1.0f + fdeg[t];                 // self-loop weight 1
        dis[node] = (dg > 0.0f) ? rsqrtf(fmaxf(dg, 1e-30f)) : 0.0f;
    }
    if (t == 0 && node0 < n && node0 + BSIZE >= n) row_ptr[n] = e;
    __syncthreads();
    cnt[t] = excl;                                 // cursor
    __syncthreads();

    // pass 2: place pairs (raw ew)
    for (int i = ebeg + t; i < eend; i += 256) {
        int2 sw = psw[i];
        int c = sw.x >> 17;
        int pos = atomicAdd(&cnt[c], 1);
        pairs[ebeg + pos] = make_int2(sw.x & 0x1FFFF, sw.y);
    }
}

// ===========================================================================
// agg over h' (= dis*h):  T = h'[i] + sum_j ew_j*h'[src_j]
// out[i] = bias + dis[i]*T   (final layer, fp32 out)
// wave = node; halves process alternating edges; lane covers 2 dims (half2)
// ===========================================================================
__global__ void agg_csr_out_kernel(const int* __restrict__ row_ptr,
                                   const int2* __restrict__ pairs,
                                   const __half* __restrict__ h,
                                   const float* __restrict__ dis,
                                   const float* __restrict__ bias,
                                   float* __restrict__ out, int n) {
    int t = threadIdx.x;
    int node = blockIdx.x * 4 + (t >> 6);
    int lane = t & 63, hf = lane >> 5, sub = lane & 31;
    if (node >= n) return;

    float2 acc = make_float2(0.0f, 0.0f);
    if (hf == 0) {
        float2 hv = __half22float2(((const __half2*)(h + (size_t)node * D))[sub]);
        acc.x = hv.x; acc.y = hv.y;
    }
    int beg = row_ptr[node], end = row_ptr[node + 1];
    #pragma unroll 8
    for (int j = beg + hf; j < end; j += 2) {
        int2 p = pairs[j];
        float w = __int_as_float(p.y);
        float2 hv = __half22float2(((const __half2*)(h + (size_t)p.x * D))[sub]);
        acc.x = fmaf(w, hv.x, acc.x);
        acc.y = fmaf(w, hv.y, acc.y);
    }
    acc.x += __shfl_xor(acc.x, 32, 64);
    acc.y += __shfl_xor(acc.y, 32, 64);
    if (hf == 0) {
        float s0 = dis[node];
        float2 bb = ((const float2*)bias)[sub];
        ((float2*)(out + (size_t)node * D))[sub] =
            make_float2(fmaf(s0, acc.x, bb.x), fmaf(s0, acc.y, bb.y));
    }
}

// ===========================================================================
// fused: agg layer1 -> relu(b1 + dis*T) tile in LDS -> GEMM W2 -> h2'=dis*(.)
// block = 32 nodes, 4 waves; wave w handles nodes w, w+4, ...
// ===========================================================================
__global__ void fused_agg_linear_kernel(const int* __restrict__ row_ptr,
                                        const int2* __restrict__ pairs,
                                        const __half* __restrict__ h1,
                                        const float* __restrict__ dis,
                                        const float* __restrict__ b1,
                                        const float* __restrict__ W2,
                                        __half* __restrict__ h2, int n) {
    __shared__ float sW[D * 65];
    __shared__ float tile[32][D];      // relu(out1) for the block's 32 nodes

    int t = threadIdx.x;
    #pragma unroll
    for (int j = 0; j < (D * D) / 256; ++j) {
        int idx = t + j * 256;
        sW[(idx >> 6) * 65 + (idx & 63)] = W2[idx];
    }

    int w = t >> 6, lane = t & 63, hf = lane >> 5, sub = lane & 31;
    int node0 = blockIdx.x * 32;

    // phase A: aggregate layer 1 into LDS tile (each wave: 8 nodes)
    for (int g = 0; g < 8; ++g) {
        int nl = g * 4 + w;
        int node = node0 + nl;
        if (node < n) {
            float2 acc = make_float2(0.0f, 0.0f);
            if (hf == 0) {
                float2 hv = __half22float2(((const __half2*)(h1 + (size_t)node * D))[sub]);
                acc.x = hv.x; acc.y = hv.y;
            }
            int beg = row_ptr[node], end = row_ptr[node + 1];
            #pragma unroll 8
            for (int j = beg + hf; j < end; j += 2) {
                int2 p = pairs[j];
                float wj = __int_as_float(p.y);
                float2 hv = __half22float2(((const __half2*)(h1 + (size_t)p.x * D))[sub]);
                acc.x = fmaf(wj, hv.x, acc.x);
                acc.y = fmaf(wj, hv.y, acc.y);
            }
            acc.x += __shfl_xor(acc.x, 32, 64);
            acc.y += __shfl_xor(acc.y, 32, 64);
            if (hf == 0) {
                float s0 = dis[node];
                float2 bb = ((const float2*)b1)[sub];
                float2 o;
                o.x = fmaxf(fmaf(s0, acc.x, bb.x), 0.0f);
                o.y = fmaxf(fmaf(s0, acc.y, bb.y), 0.0f);
                ((float2*)&tile[nl][0])[sub] = o;
            }
        }
    }
    __syncthreads();

    // phase B: h2' = dis * (tile @ W2^T), fp16 store
    int r = t >> 6, d = t & 63;
    for (int g = 0; g < 8; ++g) {
        int nl = g * 4 + r;
        int node = node0 + nl;
        if (node < n) {
            float acc = 0.0f;
            #pragma unroll
            for (int k = 0; k < D; ++k)
                acc = fmaf(tile[nl][k], sW[d * 65 + k], acc);
            h2[(size_t)node * D + d] = __float2half(acc * dis[node]);
        }
    }
}

// ===========================================================================
// CSR FALLBACK PATH (proven R2 code, fp32) — used only if ws/n don't fit
// ===========================================================================
__global__ void init_deg_counts_kernel(float* __restrict__ deg,
                                       int* __restrict__ counts, int n) {
    int i = blockIdx.x * blockDim.x + threadIdx.x;
    if (i < n) { deg[i] = 1.0f; counts[i] = 0; }
}

__global__ void edge_hist_kernel(const int* __restrict__ dst,
                                 const float* __restrict__ ew,
                                 float* __restrict__ deg,
                                 int* __restrict__ counts, int e) {
    int i = blockIdx.x * blockDim.x + threadIdx.x;
    if (i < e) {
        int c = dst[i];
        atomicAdd(&deg[c], ew[i]);
        atomicAdd(&counts[c], 1);
    }
}

__global__ void finish_dis_kernel(float* __restrict__ deg, int n) {
    int i = blockIdx.x * blockDim.x + threadIdx.x;
    if (i < n) {
        float d = deg[i];
        deg[i] = (d > 0.0f) ? rsqrtf(fmaxf(d, 1e-30f)) : 0.0f;
    }
}

#define SCAN_B 256
#define SCAN_TILE 1024

__global__ void scan1_kernel(const int* __restrict__ counts, int n,
                             int* __restrict__ row_ptr,
                             int* __restrict__ blockSums) {
    __shared__ int sdata[SCAN_B];
    int t = threadIdx.x;
    int base = blockIdx.x * SCAN_TILE + t * 4;
    int v0 = 0, v1 = 0, v2 = 0, v3 = 0;
    if (base + 3 < n) {
        int4 c = *(const int4*)(counts + base);
        v0 = c.x; v1 = c.y; v2 = c.z; v3 = c.w;
    } else {
        if (base     < n) v0 = counts[base];
        if (base + 1 < n) v1 = counts[base + 1];
        if (base + 2 < n) v2 = counts[base + 2];
        if (base + 3 < n) v3 = counts[base + 3];
    }
    int s = v0 + v1 + v2 + v3;
    sdata[t] = s;
    __syncthreads();
    for (int off = 1; off < SCAN_B; off <<= 1) {
        int x = (t >= off) ? sdata[t - off] : 0;
        __syncthreads();
        sdata[t] += x;
        __syncthreads();
    }
    int excl = sdata[t] - s;
    if (t == SCAN_B - 1) blockSums[blockIdx.x] = sdata[t];
    if (base     < n) row_ptr[base]     = excl;
    if (base + 1 < n) row_ptr[base + 1] = excl + v0;
    if (base + 2 < n) row_ptr[base + 2] = excl + v0 + v1;
    if (base + 3 < n) row_ptr[base + 3] = excl + v0 + v1 + v2;
}

__global__ void scan2_kernel(int* __restrict__ blockSums, int G) {
    if (threadIdx.x == 0 && blockIdx.x == 0) {
        int run = 0;
        for (int i = 0; i < G; ++i) { int v = blockSums[i]; blockSums[i] = run; run += v; }
    }
}

__global__ void scan3_kernel(int* __restrict__ row_ptr,
                             const int* __restrict__ blockSums,
                             int* __restrict__ cursor, int n, int e) {
    int i = blockIdx.x * blockDim.x + threadIdx.x;
    if (i < n) {
        int v = row_ptr[i] + blockSums[i >> 10];
        row_ptr[i] = v;
        cursor[i] = v;
    }
    if (i == 0) row_ptr[n] = e;
}

__global__ void build_kernel(const int* __restrict__ src,
                             const int* __restrict__ dst,
                             const float* __restrict__ ew,
                             const float* __restrict__ dis,
                             int* __restrict__ cursor,
                             int2* __restrict__ pairs, int e) {
    int i = blockIdx.x * blockDim.x + threadIdx.x;
    if (i < e) {
        int s = src[i], c = dst[i];
        float nm = dis[s] * ew[i] * dis[c];
        int pos = atomicAdd(&cursor[c], 1);
        pairs[pos] = make_int2(s, __float_as_int(nm));
    }
}

__global__ void agg_kernel(const int* __restrict__ row_ptr,
                           const int2* __restrict__ pairs,
                           const float* __restrict__ h,
                           const float* __restrict__ dis,
                           const float* __restrict__ b,
                           float* __restrict__ out, int n) {
    int t = threadIdx.x;
    int node = blockIdx.x * 4 + (t >> 6);
    int d = t & 63;
    if (node >= n) return;

    float s0 = dis[node];
    float acc = b[d] + s0 * s0 * h[(size_t)node * D + d];

    int beg = row_ptr[node], end = row_ptr[node + 1];
    #pragma unroll 4
    for (int ee = beg; ee < end; ++ee) {
        int2 p = pairs[ee];
        acc = fmaf(__int_as_float(p.y), h[(size_t)p.x * D + d], acc);
    }
    out[(size_t)node * D + d] = acc;
}

// ===========================================================================
extern "C" void kernel_launch(void* const* d_in, const int* in_sizes, int n_in,
                              void* d_out, int out_size, void* d_ws, size_t ws_size,
                              hipStream_t stream) {
    const float* x  = (const float*)d_in[0];
    const float* ea = (const float*)d_in[1];
    const float* W1 = (const float*)d_in[2];
    const float* b1 = (const float*)d_in[3];
    const float* W2 = (const float*)d_in[4];
    const float* b2 = (const float*)d_in[5];
    const int*   ei = (const int*)d_in[6];

    const int n = in_sizes[0] / D;      // 100000
    const int e = in_sizes[1];          // 1200000
    const int* src = ei;
    const int* dst = ei + e;
    float* out = (float*)d_out;

    const int B = 256;
    dim3 blk(B);
    int gN = (n + B - 1) / B;
    int gE = (e + B - 1) / B;
    int gL   = (n + 3) / 4;             // agg: 4 nodes/block
    int gL32 = (n + 31) / 32;           // linear/fused: 32 nodes/block
    int nchunk  = (e + CHUNK - 1) / CHUNK;
    int nb_used = (n + BSIZE - 1) / BSIZE;

    // ---- partition-path workspace layout (word offsets, 256-word aligned) --
    size_t o = 0;
    auto alloc = [&](size_t words) { size_t r = o; o = (o + words + 255) & ~(size_t)255; return r; };
    size_t off_hist  = alloc((size_t)NBUCKET * nchunk);
    size_t off_ofs   = alloc((size_t)NBUCKET * nchunk);
    size_t off_btot  = alloc(NBUCKET);
    size_t off_bbase = alloc(NBUCKET + 1);
    size_t off_psw   = alloc((size_t)e * 2);
    size_t off_pairs = alloc((size_t)e * 2);
    size_t off_rp    = alloc(n + 1);
    size_t off_dis   = alloc(n);
    size_t off_h1    = alloc((size_t)n * D / 2);   // __half
    size_t off_h2    = alloc((size_t)n * D / 2);   // __half
    size_t need_bytes = o * 4;

    float* ws = (float*)d_ws;

    if (ws_size >= need_bytes && n <= NBUCKET * BSIZE) {
        // ================= PARTITION PATH =================
        int*    hist  = (int*)(ws + off_hist);
        int*    ofs   = (int*)(ws + off_ofs);
        int*    btot  = (int*)(ws + off_btot);
        int*    bbase = (int*)(ws + off_bbase);
        int2*   psw   = (int2*)(ws + off_psw);
        int2*   pairs = (int2*)(ws + off_pairs);
        int*    rp    = (int*)(ws + off_rp);
        float*  dis   = ws + off_dis;
        __half* h1    = (__half*)(ws + off_h1);
        __half* h2    = (__half*)(ws + off_h2);

        part_hist_kernel<<<nchunk, blk, 0, stream>>>(dst, e, nchunk, hist);
        part_scanA_kernel<<<NBUCKET, blk, 0, stream>>>(hist, nchunk, ofs, btot);
        part_scanB_kernel<<<1, dim3(NBUCKET), 0, stream>>>(btot, bbase, e);
        part_scatter_kernel<<<nchunk, blk, 0, stream>>>(src, dst, ea, ofs, bbase, nchunk, e, psw);
        bucket_bin_kernel<<<nb_used, blk, 0, stream>>>(psw, bbase, n, e, pairs, rp, dis);

        // h1' = dis * (x @ W1^T)
        linear_kernel<false, true, float, __half><<<gL32, blk, 0, stream>>>(x, W1, dis, h1, n);
        // agg1 + relu + linear2: h2' = dis * (relu(b1 + dis*T1) @ W2^T)
        fused_agg_linear_kernel<<<gL32, blk, 0, stream>>>(rp, pairs, h1, dis, b1, W2, h2, n);
        // out = b2 + dis * T2
        agg_csr_out_kernel<<<gL, blk, 0, stream>>>(rp, pairs, h2, dis, b2, out, n);
    } else {
        // ================= CSR FALLBACK (proven R2, fp32) =================
        size_t o2 = 0;
        auto alloc2 = [&](size_t words) { size_t r = o2; o2 = (o2 + words + 255) & ~(size_t)255; return r; };
        float* dis       = ws + alloc2(n);
        int*   row_ptr   = (int*)(ws + alloc2(n + 1));
        int*   cursor    = (int*)(ws + alloc2(n));
        int*   blockSums = (int*)(ws + alloc2(512));
        int2*  pairs     = (int2*)(ws + alloc2((size_t)e * 2));
        float* h         = ws + alloc2((size_t)n * D);
        float* out1      = ws + alloc2((size_t)n * D);
        int*   counts    = cursor;
        int G = (n + SCAN_TILE - 1) / SCAN_TILE;

        init_deg_counts_kernel<<<gN, blk, 0, stream>>>(dis, counts, n);
        edge_hist_kernel<<<gE, blk, 0, stream>>>(dst, ea, dis, counts, e);
        finish_dis_kernel<<<gN, blk, 0, stream>>>(dis, n);
        scan1_kernel<<<G, blk, 0, stream>>>(counts, n, row_ptr, blockSums);
        scan2_kernel<<<1, blk, 0, stream>>>(blockSums, G);
        scan3_kernel<<<gN, blk, 0, stream>>>(row_ptr, blockSums, cursor, n, e);
        build_kernel<<<gE, blk, 0, stream>>>(src, dst, ea, dis, cursor, pairs, e);

        linear_kernel<false, false, float, float><<<gL32, blk, 0, stream>>>(x, W1, nullptr, h, n);
        agg_kernel<<<gL, blk, 0, stream>>>(row_ptr, pairs, h, dis, b1, out1, n);

        linear_kernel<true, false, float, float><<<gL32, blk, 0, stream>>>(out1, W2, nullptr, h, n);
        agg_kernel<<<gL, blk, 0, stream>>>(row_ptr, pairs, h, dis, b2, out, n);
    }
}

// Round 10
// 266.282 us; speedup vs baseline: 1.0458x; 1.0458x over previous
//
#include <hip/hip_runtime.h>
#include <hip/hip_fp16.h>

#define D 64
#define CHUNK 4096
#define BSIZE 256          // nodes per bucket (dst >> 8)
#define NBUCKET 512        // covers up to 131072 nodes (src fits in 17 bits)

// ---- load/store helpers (fp32 or fp16 storage, fp32 compute) --------------
static __device__ __forceinline__ float ldf(const float* p)  { return *p; }
static __device__ __forceinline__ float ldf(const __half* p) { return __half2float(*p); }
static __device__ __forceinline__ void  stf(float* p, float v)  { *p = v; }
static __device__ __forceinline__ void  stf(__half* p, float v) { *p = __float2half(v); }

// ===========================================================================
// h = scale * (optional relu)(x) @ W^T   [n,64]x[64,64]; 32 nodes/block
// ===========================================================================
template <bool RELU, bool SCALE, typename IN_T, typename OUT_T>
__global__ void linear_kernel(const IN_T* __restrict__ x,
                              const float* __restrict__ W,
                              const float* __restrict__ dis,
                              OUT_T* __restrict__ h, int n) {
    __shared__ float sW[D * 65];
    __shared__ float sx[4][D];

    int t = threadIdx.x;
    #pragma unroll
    for (int j = 0; j < (D * D) / 256; ++j) {
        int idx = t + j * 256;
        int dd = idx >> 6, k = idx & 63;
        sW[dd * 65 + k] = W[idx];
    }

    int r = t >> 6, d = t & 63;
    int node0 = blockIdx.x * 32;
    for (int g = 0; g < 8; ++g) {
        int node = node0 + g * 4 + r;
        __syncthreads();                   // covers sW (g=0) and sx reuse
        float v = (node < n) ? ldf(&x[(size_t)node * D + d]) : 0.0f;
        if (RELU) v = fmaxf(v, 0.0f);
        sx[r][d] = v;
        __syncthreads();
        if (node < n) {
            float acc = 0.0f;
            #pragma unroll
            for (int k = 0; k < D; ++k)
                acc = fmaf(sx[r][k], sW[d * 65 + k], acc);
            if (SCALE) acc *= dis[node];
            stf(&h[(size_t)node * D + d], acc);
        }
    }
}

// ===========================================================================
// PARTITION PATH
// ===========================================================================
// A: per-chunk bucket histogram (LDS atomics only); 512 buckets, 256 threads
__global__ void part_hist_kernel(const int* __restrict__ dst, int e,
                                 int nchunk, int* __restrict__ hist) {
    __shared__ int cnt[NBUCKET];
    int t = threadIdx.x;
    cnt[t] = 0; cnt[t + 256] = 0;
    __syncthreads();
    int base = blockIdx.x * CHUNK;
    int end = min(base + CHUNK, e);
    int nv = (end - base) >> 2;
    for (int g = t; g < nv; g += 256) {
        int4 c4 = *(const int4*)(dst + base + g * 4);
        atomicAdd(&cnt[c4.x >> 8], 1);
        atomicAdd(&cnt[c4.y >> 8], 1);
        atomicAdd(&cnt[c4.z >> 8], 1);
        atomicAdd(&cnt[c4.w >> 8], 1);
    }
    if (t < ((end - base) & 3))
        atomicAdd(&cnt[dst[base + nv * 4 + t] >> 8], 1);
    __syncthreads();
    hist[(size_t)t * nchunk + blockIdx.x] = cnt[t];
    hist[(size_t)(t + 256) * nchunk + blockIdx.x] = cnt[t + 256];
}

// B1: per-bucket exclusive scan over its chunk counts (one block per bucket)
__global__ void part_scanA_kernel(const int* __restrict__ hist, int nchunk,
                                  int* __restrict__ ofs,
                                  int* __restrict__ btot) {
    __shared__ int sd[256];
    int b = blockIdx.x, t = threadIdx.x;
    int carry = 0;
    for (int base = 0; base < nchunk; base += 256) {
        int c = base + t;
        int v = (c < nchunk) ? hist[(size_t)b * nchunk + c] : 0;
        sd[t] = v;
        __syncthreads();
        for (int off = 1; off < 256; off <<= 1) {
            int x = (t >= off) ? sd[t - off] : 0;
            __syncthreads();
            sd[t] += x;
            __syncthreads();
        }
        if (c < nchunk) ofs[(size_t)b * nchunk + c] = carry + sd[t] - v;
        carry += sd[255];
        __syncthreads();
    }
    if (t == 0) btot[b] = carry;
}

// B2: scan NBUCKET totals -> bucketBase (single block of NBUCKET threads)
__global__ void part_scanB_kernel(const int* __restrict__ btot,
                                  int* __restrict__ bucketBase, int e) {
    __shared__ int sd[NBUCKET];
    int t = threadIdx.x;
    int v = btot[t];
    sd[t] = v;
    __syncthreads();
    for (int off = 1; off < NBUCKET; off <<= 1) {
        int x = (t >= off) ? sd[t - off] : 0;
        __syncthreads();
        sd[t] += x;
        __syncthreads();
    }
    bucketBase[t] = sd[t] - v;
    if (t == NBUCKET - 1) bucketBase[NBUCKET] = e;
}

// C: scatter edges into bucket-contiguous regions; pack (src | dlow<<17, ew)
__global__ void part_scatter_kernel(const int* __restrict__ src,
                                    const int* __restrict__ dst,
                                    const float* __restrict__ ew,
                                    const int* __restrict__ ofs,
                                    const int* __restrict__ bucketBase,
                                    int nchunk, int e,
                                    int2* __restrict__ psw) {
    __shared__ int cur[NBUCKET];
    int t = threadIdx.x;
    cur[t]       = bucketBase[t]       + ofs[(size_t)t * nchunk + blockIdx.x];
    cur[t + 256] = bucketBase[t + 256] + ofs[(size_t)(t + 256) * nchunk + blockIdx.x];
    __syncthreads();
    int base = blockIdx.x * CHUNK;
    int end = min(base + CHUNK, e);
    int nv = (end - base) >> 2;
    for (int g = t; g < nv; g += 256) {
        int i = base + g * 4;
        int4   c4 = *(const int4*)(dst + i);
        int4   s4 = *(const int4*)(src + i);
        float4 w4 = *(const float4*)(ew + i);
        int p0 = atomicAdd(&cur[c4.x >> 8], 1);
        int p1 = atomicAdd(&cur[c4.y >> 8], 1);
        int p2 = atomicAdd(&cur[c4.z >> 8], 1);
        int p3 = atomicAdd(&cur[c4.w >> 8], 1);
        psw[p0] = make_int2(s4.x | ((c4.x & 255) << 17), __float_as_int(w4.x));
        psw[p1] = make_int2(s4.y | ((c4.y & 255) << 17), __float_as_int(w4.y));
        psw[p2] = make_int2(s4.z | ((c4.z & 255) << 17), __float_as_int(w4.z));
        psw[p3] = make_int2(s4.w | ((c4.w & 255) << 17), __float_as_int(w4.w));
    }
    if (t < ((end - base) & 3)) {
        int k = base + nv * 4 + t;
        int c = dst[k];
        int p = atomicAdd(&cur[c >> 8], 1);
        psw[p] = make_int2(src[k] | ((c & 255) << 17), __float_as_int(ew[k]));
    }
}

// D: per-bucket binning -> CSR pairs (raw ew), row_ptr, dis
__global__ void bucket_bin_kernel(const int2* __restrict__ psw,
                                  const int* __restrict__ bucketBase,
                                  int n, int e,
                                  int2* __restrict__ pairs,
                                  int* __restrict__ row_ptr,
                                  float* __restrict__ dis) {
    __shared__ int   cnt[BSIZE];
    __shared__ float fdeg[BSIZE];
    __shared__ int   sc[BSIZE];

    int t = threadIdx.x;
    int b = blockIdx.x;
    int node0 = b * BSIZE;
    int ebeg = bucketBase[b], eend = bucketBase[b + 1];

    cnt[t] = 0;
    fdeg[t] = 0.0f;
    __syncthreads();

    // pass 1: node counts + weighted degree (LDS atomics)
    for (int i = ebeg + t; i < eend; i += 256) {
        int2 sw = psw[i];
        int c = sw.x >> 17;
        atomicAdd(&cnt[c], 1);
        atomicAdd(&fdeg[c], __int_as_float(sw.y));
    }
    __syncthreads();

    // exclusive scan of 256 counts
    int v = cnt[t];
    sc[t] = v;
    __syncthreads();
    for (int off = 1; off < 256; off <<= 1) {
        int x = (t >= off) ? sc[t - off] : 0;
        __syncthreads();
        sc[t] += x;
        __syncthreads();
    }
    int excl = sc[t] - v;

    int node = node0 + t;
    if (node < n) {
        row_ptr[node] = ebeg + excl;
        float dg = 1.0f + fdeg[t];                 // self-loop weight 1
        dis[node] = (dg > 0.0f) ? rsqrtf(fmaxf(dg, 1e-30f)) : 0.0f;
    }
    if (t == 0 && node0 < n && node0 + BSIZE >= n) row_ptr[n] = e;
    __syncthreads();
    cnt[t] = excl;                                 // cursor
    __syncthreads();

    // pass 2: place pairs (raw ew)
    for (int i = ebeg + t; i < eend; i += 256) {
        int2 sw = psw[i];
        int c = sw.x >> 17;
        int pos = atomicAdd(&cnt[c], 1);
        pairs[ebeg + pos] = make_int2(sw.x & 0x1FFFF, sw.y);
    }
}

// ===========================================================================
// agg over h' (= dis*h):  T = h'[i] + sum_j ew_j*h'[src_j]
// out[i] = (RELU?) relu(bias + dis[i]*T) : bias + dis[i]*T
// wave = node; halves process alternating edges; lane covers 2 dims (half2)
// ===========================================================================
template <bool RELU, typename OUT_T>
__global__ void agg_csr_kernel(const int* __restrict__ row_ptr,
                               const int2* __restrict__ pairs,
                               const __half* __restrict__ h,
                               const float* __restrict__ dis,
                               const float* __restrict__ bias,
                               OUT_T* __restrict__ out, int n) {
    int t = threadIdx.x;
    int node = blockIdx.x * 4 + (t >> 6);
    int lane = t & 63, hf = lane >> 5, sub = lane & 31;
    if (node >= n) return;

    float2 acc = make_float2(0.0f, 0.0f);
    if (hf == 0) {
        float2 hv = __half22float2(((const __half2*)(h + (size_t)node * D))[sub]);
        acc.x = hv.x; acc.y = hv.y;
    }
    int beg = row_ptr[node], end = row_ptr[node + 1];
    #pragma unroll 8
    for (int j = beg + hf; j < end; j += 2) {
        int2 p = pairs[j];                 // uniform within half-wave
        float w = __int_as_float(p.y);
        float2 hv = __half22float2(((const __half2*)(h + (size_t)p.x * D))[sub]);
        acc.x = fmaf(w, hv.x, acc.x);
        acc.y = fmaf(w, hv.y, acc.y);
    }
    acc.x += __shfl_xor(acc.x, 32, 64);
    acc.y += __shfl_xor(acc.y, 32, 64);
    if (hf == 0) {
        float s0 = dis[node];
        float2 bb = ((const float2*)bias)[sub];
        float ox = fmaf(s0, acc.x, bb.x);
        float oy = fmaf(s0, acc.y, bb.y);
        if (RELU) { ox = fmaxf(ox, 0.0f); oy = fmaxf(oy, 0.0f); }
        if constexpr (sizeof(OUT_T) == 2) {
            ((__half2*)(out + (size_t)node * D))[sub] =
                __float22half2_rn(make_float2(ox, oy));
        } else {
            ((float2*)(out + (size_t)node * D))[sub] = make_float2(ox, oy);
        }
    }
}

// ===========================================================================
// CSR FALLBACK PATH (proven R2 code, fp32) — used only if ws/n don't fit
// ===========================================================================
__global__ void init_deg_counts_kernel(float* __restrict__ deg,
                                       int* __restrict__ counts, int n) {
    int i = blockIdx.x * blockDim.x + threadIdx.x;
    if (i < n) { deg[i] = 1.0f; counts[i] = 0; }
}

__global__ void edge_hist_kernel(const int* __restrict__ dst,
                                 const float* __restrict__ ew,
                                 float* __restrict__ deg,
                                 int* __restrict__ counts, int e) {
    int i = blockIdx.x * blockDim.x + threadIdx.x;
    if (i < e) {
        int c = dst[i];
        atomicAdd(&deg[c], ew[i]);
        atomicAdd(&counts[c], 1);
    }
}

__global__ void finish_dis_kernel(float* __restrict__ deg, int n) {
    int i = blockIdx.x * blockDim.x + threadIdx.x;
    if (i < n) {
        float d = deg[i];
        deg[i] = (d > 0.0f) ? rsqrtf(fmaxf(d, 1e-30f)) : 0.0f;
    }
}

#define SCAN_B 256
#define SCAN_TILE 1024

__global__ void scan1_kernel(const int* __restrict__ counts, int n,
                             int* __restrict__ row_ptr,
                             int* __restrict__ blockSums) {
    __shared__ int sdata[SCAN_B];
    int t = threadIdx.x;
    int base = blockIdx.x * SCAN_TILE + t * 4;
    int v0 = 0, v1 = 0, v2 = 0, v3 = 0;
    if (base + 3 < n) {
        int4 c = *(const int4*)(counts + base);
        v0 = c.x; v1 = c.y; v2 = c.z; v3 = c.w;
    } else {
        if (base     < n) v0 = counts[base];
        if (base + 1 < n) v1 = counts[base + 1];
        if (base + 2 < n) v2 = counts[base + 2];
        if (base + 3 < n) v3 = counts[base + 3];
    }
    int s = v0 + v1 + v2 + v3;
    sdata[t] = s;
    __syncthreads();
    for (int off = 1; off < SCAN_B; off <<= 1) {
        int x = (t >= off) ? sdata[t - off] : 0;
        __syncthreads();
        sdata[t] += x;
        __syncthreads();
    }
    int excl = sdata[t] - s;
    if (t == SCAN_B - 1) blockSums[blockIdx.x] = sdata[t];
    if (base     < n) row_ptr[base]     = excl;
    if (base + 1 < n) row_ptr[base + 1] = excl + v0;
    if (base + 2 < n) row_ptr[base + 2] = excl + v0 + v1;
    if (base + 3 < n) row_ptr[base + 3] = excl + v0 + v1 + v2;
}

__global__ void scan2_kernel(int* __restrict__ blockSums, int G) {
    if (threadIdx.x == 0 && blockIdx.x == 0) {
        int run = 0;
        for (int i = 0; i < G; ++i) { int v = blockSums[i]; blockSums[i] = run; run += v; }
    }
}

__global__ void scan3_kernel(int* __restrict__ row_ptr,
                             const int* __restrict__ blockSums,
                             int* __restrict__ cursor, int n, int e) {
    int i = blockIdx.x * blockDim.x + threadIdx.x;
    if (i < n) {
        int v = row_ptr[i] + blockSums[i >> 10];
        row_ptr[i] = v;
        cursor[i] = v;
    }
    if (i == 0) row_ptr[n] = e;
}

__global__ void build_kernel(const int* __restrict__ src,
                             const int* __restrict__ dst,
                             const float* __restrict__ ew,
                             const float* __restrict__ dis,
                             int* __restrict__ cursor,
                             int2* __restrict__ pairs, int e) {
    int i = blockIdx.x * blockDim.x + threadIdx.x;
    if (i < e) {
        int s = src[i], c = dst[i];
        float nm = dis[s] * ew[i] * dis[c];
        int pos = atomicAdd(&cursor[c], 1);
        pairs[pos] = make_int2(s, __float_as_int(nm));
    }
}

__global__ void agg_kernel(const int* __restrict__ row_ptr,
                           const int2* __restrict__ pairs,
                           const float* __restrict__ h,
                           const float* __restrict__ dis,
                           const float* __restrict__ b,
                           float* __restrict__ out, int n) {
    int t = threadIdx.x;
    int node = blockIdx.x * 4 + (t >> 6);
    int d = t & 63;
    if (node >= n) return;

    float s0 = dis[node];
    float acc = b[d] + s0 * s0 * h[(size_t)node * D + d];

    int beg = row_ptr[node], end = row_ptr[node + 1];
    #pragma unroll 4
    for (int ee = beg; ee < end; ++ee) {
        int2 p = pairs[ee];
        acc = fmaf(__int_as_float(p.y), h[(size_t)p.x * D + d], acc);
    }
    out[(size_t)node * D + d] = acc;
}

// ===========================================================================
extern "C" void kernel_launch(void* const* d_in, const int* in_sizes, int n_in,
                              void* d_out, int out_size, void* d_ws, size_t ws_size,
                              hipStream_t stream) {
    const float* x  = (const float*)d_in[0];
    const float* ea = (const float*)d_in[1];
    const float* W1 = (const float*)d_in[2];
    const float* b1 = (const float*)d_in[3];
    const float* W2 = (const float*)d_in[4];
    const float* b2 = (const float*)d_in[5];
    const int*   ei = (const int*)d_in[6];

    const int n = in_sizes[0] / D;      // 100000
    const int e = in_sizes[1];          // 1200000
    const int* src = ei;
    const int* dst = ei + e;
    float* out = (float*)d_out;

    const int B = 256;
    dim3 blk(B);
    int gN = (n + B - 1) / B;
    int gE = (e + B - 1) / B;
    int gL   = (n + 3) / 4;             // agg: 4 nodes/block
    int gL32 = (n + 31) / 32;           // linear: 32 nodes/block
    int nchunk  = (e + CHUNK - 1) / CHUNK;
    int nb_used = (n + BSIZE - 1) / BSIZE;

    // ---- partition-path workspace layout (word offsets, 256-word aligned) --
    size_t o = 0;
    auto alloc = [&](size_t words) { size_t r = o; o = (o + words + 255) & ~(size_t)255; return r; };
    size_t off_hist  = alloc((size_t)NBUCKET * nchunk);
    size_t off_ofs   = alloc((size_t)NBUCKET * nchunk);
    size_t off_btot  = alloc(NBUCKET);
    size_t off_bbase = alloc(NBUCKET + 1);
    size_t off_psw   = alloc((size_t)e * 2);
    size_t off_pairs = alloc((size_t)e * 2);
    size_t off_rp    = alloc(n + 1);
    size_t off_dis   = alloc(n);
    size_t off_h1    = alloc((size_t)n * D / 2);   // __half
    size_t off_o1    = alloc((size_t)n * D / 2);   // __half
    size_t need_bytes = o * 4;

    float* ws = (float*)d_ws;

    if (ws_size >= need_bytes && n <= NBUCKET * BSIZE) {
        // ================= PARTITION PATH =================
        int*    hist  = (int*)(ws + off_hist);
        int*    ofs   = (int*)(ws + off_ofs);
        int*    btot  = (int*)(ws + off_btot);
        int*    bbase = (int*)(ws + off_bbase);
        int2*   psw   = (int2*)(ws + off_psw);
        int2*   pairs = (int2*)(ws + off_pairs);
        int*    rp    = (int*)(ws + off_rp);
        float*  dis   = ws + off_dis;
        __half* h1    = (__half*)(ws + off_h1);
        __half* o1    = (__half*)(ws + off_o1);

        part_hist_kernel<<<nchunk, blk, 0, stream>>>(dst, e, nchunk, hist);
        part_scanA_kernel<<<NBUCKET, blk, 0, stream>>>(hist, nchunk, ofs, btot);
        part_scanB_kernel<<<1, dim3(NBUCKET), 0, stream>>>(btot, bbase, e);
        part_scatter_kernel<<<nchunk, blk, 0, stream>>>(src, dst, ea, ofs, bbase, nchunk, e, psw);
        bucket_bin_kernel<<<nb_used, blk, 0, stream>>>(psw, bbase, n, e, pairs, rp, dis);

        // h1' = dis * (x @ W1^T)
        linear_kernel<false, true, float, __half><<<gL32, blk, 0, stream>>>(x, W1, dis, h1, n);
        // o1 = relu(b1 + dis * T1)
        agg_csr_kernel<true, __half><<<gL, blk, 0, stream>>>(rp, pairs, h1, dis, b1, o1, n);
        // h2' = dis * (o1 @ W2^T)   (reuse h1 buffer)
        linear_kernel<false, true, __half, __half><<<gL32, blk, 0, stream>>>(o1, W2, dis, h1, n);
        // out = b2 + dis * T2
        agg_csr_kernel<false, float><<<gL, blk, 0, stream>>>(rp, pairs, h1, dis, b2, out, n);
    } else {
        // ================= CSR FALLBACK (proven R2, fp32) =================
        size_t o2 = 0;
        auto alloc2 = [&](size_t words) { size_t r = o2; o2 = (o2 + words + 255) & ~(size_t)255; return r; };
        float* dis       = ws + alloc2(n);
        int*   row_ptr   = (int*)(ws + alloc2(n + 1));
        int*   cursor    = (int*)(ws + alloc2(n));
        int*   blockSums = (int*)(ws + alloc2(512));
        int2*  pairs     = (int2*)(ws + alloc2((size_t)e * 2));
        float* h         = ws + alloc2((size_t)n * D);
        float* out1      = ws + alloc2((size_t)n * D);
        int*   counts    = cursor;
        int G = (n + SCAN_TILE - 1) / SCAN_TILE;

        init_deg_counts_kernel<<<gN, blk, 0, stream>>>(dis, counts, n);
        edge_hist_kernel<<<gE, blk, 0, stream>>>(dst, ea, dis, counts, e);
        finish_dis_kernel<<<gN, blk, 0, stream>>>(dis, n);
        scan1_kernel<<<G, blk, 0, stream>>>(counts, n, row_ptr, blockSums);
        scan2_kernel<<<1, blk, 0, stream>>>(blockSums, G);
        scan3_kernel<<<gN, blk, 0, stream>>>(row_ptr, blockSums, cursor, n, e);
        build_kernel<<<gE, blk, 0, stream>>>(src, dst, ea, dis, cursor, pairs, e);

        linear_kernel<false, false, float, float><<<gL32, blk, 0, stream>>>(x, W1, nullptr, h, n);
        agg_kernel<<<gL, blk, 0, stream>>>(row_ptr, pairs, h, dis, b1, out1, n);

        linear_kernel<true, false, float, float><<<gL32, blk, 0, stream>>>(out1, W2, nullptr, h, n);
        agg_kernel<<<gL, blk, 0, stream>>>(row_ptr, pairs, h, dis, b2, out, n);
    }
}

// Round 11
// 223.283 us; speedup vs baseline: 1.2472x; 1.1926x over previous
//
#include <hip/hip_runtime.h>
#include <hip/hip_fp16.h>

#define D 64
#define CHUNK 4096
#define BSIZE 256          // nodes per bucket (dst >> 8)
#define NBUCKET 512        // covers up to 131072 nodes (src fits in 17 bits)

// ---- load/store helpers (fp32 or fp16 storage, fp32 compute) --------------
static __device__ __forceinline__ float ldf(const float* p)  { return *p; }
static __device__ __forceinline__ float ldf(const __half* p) { return __half2float(*p); }
static __device__ __forceinline__ void  stf(float* p, float v)  { *p = v; }
static __device__ __forceinline__ void  stf(__half* p, float v) { *p = __float2half(v); }

// ===========================================================================
// h = scale * (optional relu)(x) @ W^T   [n,64]x[64,64]; 32 nodes/block
// ===========================================================================
template <bool RELU, bool SCALE, typename IN_T, typename OUT_T>
__global__ void linear_kernel(const IN_T* __restrict__ x,
                              const float* __restrict__ W,
                              const float* __restrict__ dis,
                              OUT_T* __restrict__ h, int n) {
    __shared__ float sW[D * 65];
    __shared__ float sx[4][D];

    int t = threadIdx.x;
    #pragma unroll
    for (int j = 0; j < (D * D) / 256; ++j) {
        int idx = t + j * 256;
        int dd = idx >> 6, k = idx & 63;
        sW[dd * 65 + k] = W[idx];
    }

    int r = t >> 6, d = t & 63;
    int node0 = blockIdx.x * 32;
    for (int g = 0; g < 8; ++g) {
        int node = node0 + g * 4 + r;
        __syncthreads();                   // covers sW (g=0) and sx reuse
        float v = (node < n) ? ldf(&x[(size_t)node * D + d]) : 0.0f;
        if (RELU) v = fmaxf(v, 0.0f);
        sx[r][d] = v;
        __syncthreads();
        if (node < n) {
            float acc = 0.0f;
            #pragma unroll
            for (int k = 0; k < D; ++k)
                acc = fmaf(sx[r][k], sW[d * 65 + k], acc);
            if (SCALE) acc *= dis[node];
            stf(&h[(size_t)node * D + d], acc);
        }
    }
}

// ===========================================================================
// PARTITION PATH
// ===========================================================================
// A: per-chunk bucket histogram (LDS atomics only); 512 buckets, 256 threads
__global__ void part_hist_kernel(const int* __restrict__ dst, int e,
                                 int nchunk, int* __restrict__ hist) {
    __shared__ int cnt[NBUCKET];
    int t = threadIdx.x;
    cnt[t] = 0; cnt[t + 256] = 0;
    __syncthreads();
    int base = blockIdx.x * CHUNK;
    int end = min(base + CHUNK, e);
    int nv = (end - base) >> 2;
    for (int g = t; g < nv; g += 256) {
        int4 c4 = *(const int4*)(dst + base + g * 4);
        atomicAdd(&cnt[c4.x >> 8], 1);
        atomicAdd(&cnt[c4.y >> 8], 1);
        atomicAdd(&cnt[c4.z >> 8], 1);
        atomicAdd(&cnt[c4.w >> 8], 1);
    }
    if (t < ((end - base) & 3))
        atomicAdd(&cnt[dst[base + nv * 4 + t] >> 8], 1);
    __syncthreads();
    hist[(size_t)t * nchunk + blockIdx.x] = cnt[t];
    hist[(size_t)(t + 256) * nchunk + blockIdx.x] = cnt[t + 256];
}

// B1: per-bucket exclusive scan over its chunk counts (one block per bucket)
__global__ void part_scanA_kernel(const int* __restrict__ hist, int nchunk,
                                  int* __restrict__ ofs,
                                  int* __restrict__ btot) {
    __shared__ int sd[256];
    int b = blockIdx.x, t = threadIdx.x;
    int carry = 0;
    for (int base = 0; base < nchunk; base += 256) {
        int c = base + t;
        int v = (c < nchunk) ? hist[(size_t)b * nchunk + c] : 0;
        sd[t] = v;
        __syncthreads();
        for (int off = 1; off < 256; off <<= 1) {
            int x = (t >= off) ? sd[t - off] : 0;
            __syncthreads();
            sd[t] += x;
            __syncthreads();
        }
        if (c < nchunk) ofs[(size_t)b * nchunk + c] = carry + sd[t] - v;
        carry += sd[255];
        __syncthreads();
    }
    if (t == 0) btot[b] = carry;
}

// B2: scan NBUCKET totals -> bucketBase (single block of NBUCKET threads)
__global__ void part_scanB_kernel(const int* __restrict__ btot,
                                  int* __restrict__ bucketBase, int e) {
    __shared__ int sd[NBUCKET];
    int t = threadIdx.x;
    int v = btot[t];
    sd[t] = v;
    __syncthreads();
    for (int off = 1; off < NBUCKET; off <<= 1) {
        int x = (t >= off) ? sd[t - off] : 0;
        __syncthreads();
        sd[t] += x;
        __syncthreads();
    }
    bucketBase[t] = sd[t] - v;
    if (t == NBUCKET - 1) bucketBase[NBUCKET] = e;
}

// C: scatter edges into bucket-contiguous regions; pack (src | dlow<<17, ew)
__global__ void part_scatter_kernel(const int* __restrict__ src,
                                    const int* __restrict__ dst,
                                    const float* __restrict__ ew,
                                    const int* __restrict__ ofs,
                                    const int* __restrict__ bucketBase,
                                    int nchunk, int e,
                                    int2* __restrict__ psw) {
    __shared__ int cur[NBUCKET];
    int t = threadIdx.x;
    cur[t]       = bucketBase[t]       + ofs[(size_t)t * nchunk + blockIdx.x];
    cur[t + 256] = bucketBase[t + 256] + ofs[(size_t)(t + 256) * nchunk + blockIdx.x];
    __syncthreads();
    int base = blockIdx.x * CHUNK;
    int end = min(base + CHUNK, e);
    int nv = (end - base) >> 2;
    for (int g = t; g < nv; g += 256) {
        int i = base + g * 4;
        int4   c4 = *(const int4*)(dst + i);
        int4   s4 = *(const int4*)(src + i);
        float4 w4 = *(const float4*)(ew + i);
        int p0 = atomicAdd(&cur[c4.x >> 8], 1);
        int p1 = atomicAdd(&cur[c4.y >> 8], 1);
        int p2 = atomicAdd(&cur[c4.z >> 8], 1);
        int p3 = atomicAdd(&cur[c4.w >> 8], 1);
        psw[p0] = make_int2(s4.x | ((c4.x & 255) << 17), __float_as_int(w4.x));
        psw[p1] = make_int2(s4.y | ((c4.y & 255) << 17), __float_as_int(w4.y));
        psw[p2] = make_int2(s4.z | ((c4.z & 255) << 17), __float_as_int(w4.z));
        psw[p3] = make_int2(s4.w | ((c4.w & 255) << 17), __float_as_int(w4.w));
    }
    if (t < ((end - base) & 3)) {
        int k = base + nv * 4 + t;
        int c = dst[k];
        int p = atomicAdd(&cur[c >> 8], 1);
        psw[p] = make_int2(src[k] | ((c & 255) << 17), __float_as_int(ew[k]));
    }
}

// D: per-bucket binning -> CSR pairs (raw ew), row_ptr, dis
__global__ void bucket_bin_kernel(const int2* __restrict__ psw,
                                  const int* __restrict__ bucketBase,
                                  int n, int e,
                                  int2* __restrict__ pairs,
                                  int* __restrict__ row_ptr,
                                  float* __restrict__ dis) {
    __shared__ int   cnt[BSIZE];
    __shared__ float fdeg[BSIZE];
    __shared__ int   sc[BSIZE];

    int t = threadIdx.x;
    int b = blockIdx.x;
    int node0 = b * BSIZE;
    int ebeg = bucketBase[b], eend = bucketBase[b + 1];

    cnt[t] = 0;
    fdeg[t] = 0.0f;
    __syncthreads();

    // pass 1: node counts + weighted degree (LDS atomics)
    for (int i = ebeg + t; i < eend; i += 256) {
        int2 sw = psw[i];
        int c = sw.x >> 17;
        atomicAdd(&cnt[c], 1);
        atomicAdd(&fdeg[c], __int_as_float(sw.y));
    }
    __syncthreads();

    // exclusive scan of 256 counts
    int v = cnt[t];
    sc[t] = v;
    __syncthreads();
    for (int off = 1; off < 256; off <<= 1) {
        int x = (t >= off) ? sc[t - off] : 0;
        __syncthreads();
        sc[t] += x;
        __syncthreads();
    }
    int excl = sc[t] - v;

    int node = node0 + t;
    if (node < n) {
        row_ptr[node] = ebeg + excl;
        float dg = 1.0f + fdeg[t];                 // self-loop weight 1
        dis[node] = (dg > 0.0f) ? rsqrtf(fmaxf(dg, 1e-30f)) : 0.0f;
    }
    if (t == 0 && node0 < n && node0 + BSIZE >= n) row_ptr[n] = e;
    __syncthreads();
    cnt[t] = excl;                                 // cursor
    __syncthreads();

    // pass 2: place pairs (raw ew)
    for (int i = ebeg + t; i < eend; i += 256) {
        int2 sw = psw[i];
        int c = sw.x >> 17;
        int pos = atomicAdd(&cnt[c], 1);
        pairs[ebeg + pos] = make_int2(sw.x & 0x1FFFF, sw.y);
    }
}

// ===========================================================================
// agg over h' (= dis*h):  T = h'[i] + sum_j ew_j*h'[src_j]
// out[i] = (RELU?) relu(bias + dis[i]*T) : bias + dis[i]*T
// wave = node; 4 quarter-waves process 4 consecutive edges concurrently;
// lane covers 4 dims (2x half2, 8B) -> 16 lanes span the 128B row.
// ===========================================================================
template <bool RELU, typename OUT_T>
__global__ void agg_csr_kernel(const int* __restrict__ row_ptr,
                               const int2* __restrict__ pairs,
                               const __half* __restrict__ h,
                               const float* __restrict__ dis,
                               const float* __restrict__ bias,
                               OUT_T* __restrict__ out, int n) {
    int t = threadIdx.x;
    int node = blockIdx.x * 4 + (t >> 6);
    int lane = t & 63, q = lane >> 4, sub = lane & 15;
    if (node >= n) return;

    float4 acc = make_float4(0.0f, 0.0f, 0.0f, 0.0f);
    if (q == 0) {
        float2 raw = ((const float2*)(h + (size_t)node * D))[sub];
        float2 a = __half22float2(*(const __half2*)&raw.x);
        float2 b = __half22float2(*(const __half2*)&raw.y);
        acc = make_float4(a.x, a.y, b.x, b.y);
    }
    int beg = row_ptr[node], end = row_ptr[node + 1];
    #pragma unroll 2
    for (int j = beg + q; j < end; j += 4) {
        int2 p = pairs[j];                 // 4 quarters read 4 consecutive pairs
        float w = __int_as_float(p.y);
        float2 raw = ((const float2*)(h + (size_t)p.x * D))[sub];
        float2 a = __half22float2(*(const __half2*)&raw.x);
        float2 b = __half22float2(*(const __half2*)&raw.y);
        acc.x = fmaf(w, a.x, acc.x);
        acc.y = fmaf(w, a.y, acc.y);
        acc.z = fmaf(w, b.x, acc.z);
        acc.w = fmaf(w, b.y, acc.w);
    }
    // combine the four quarters
    acc.x += __shfl_xor(acc.x, 16, 64);
    acc.y += __shfl_xor(acc.y, 16, 64);
    acc.z += __shfl_xor(acc.z, 16, 64);
    acc.w += __shfl_xor(acc.w, 16, 64);
    acc.x += __shfl_xor(acc.x, 32, 64);
    acc.y += __shfl_xor(acc.y, 32, 64);
    acc.z += __shfl_xor(acc.z, 32, 64);
    acc.w += __shfl_xor(acc.w, 32, 64);

    if (q == 0) {
        float s0 = dis[node];
        float4 bb = ((const float4*)bias)[sub];
        float o0 = fmaf(s0, acc.x, bb.x);
        float o1 = fmaf(s0, acc.y, bb.y);
        float o2 = fmaf(s0, acc.z, bb.z);
        float o3 = fmaf(s0, acc.w, bb.w);
        if (RELU) {
            o0 = fmaxf(o0, 0.0f); o1 = fmaxf(o1, 0.0f);
            o2 = fmaxf(o2, 0.0f); o3 = fmaxf(o3, 0.0f);
        }
        if constexpr (sizeof(OUT_T) == 2) {
            __half2 r0 = __float22half2_rn(make_float2(o0, o1));
            __half2 r1 = __float22half2_rn(make_float2(o2, o3));
            uint2 u = make_uint2(*(unsigned int*)&r0, *(unsigned int*)&r1);
            ((uint2*)(out + (size_t)node * D))[sub] = u;
        } else {
            ((float4*)(out + (size_t)node * D))[sub] = make_float4(o0, o1, o2, o3);
        }
    }
}

// ===========================================================================
// CSR FALLBACK PATH (proven R2 code, fp32) — used only if ws/n don't fit
// ===========================================================================
__global__ void init_deg_counts_kernel(float* __restrict__ deg,
                                       int* __restrict__ counts, int n) {
    int i = blockIdx.x * blockDim.x + threadIdx.x;
    if (i < n) { deg[i] = 1.0f; counts[i] = 0; }
}

__global__ void edge_hist_kernel(const int* __restrict__ dst,
                                 const float* __restrict__ ew,
                                 float* __restrict__ deg,
                                 int* __restrict__ counts, int e) {
    int i = blockIdx.x * blockDim.x + threadIdx.x;
    if (i < e) {
        int c = dst[i];
        atomicAdd(&deg[c], ew[i]);
        atomicAdd(&counts[c], 1);
    }
}

__global__ void finish_dis_kernel(float* __restrict__ deg, int n) {
    int i = blockIdx.x * blockDim.x + threadIdx.x;
    if (i < n) {
        float d = deg[i];
        deg[i] = (d > 0.0f) ? rsqrtf(fmaxf(d, 1e-30f)) : 0.0f;
    }
}

#define SCAN_B 256
#define SCAN_TILE 1024

__global__ void scan1_kernel(const int* __restrict__ counts, int n,
                             int* __restrict__ row_ptr,
                             int* __restrict__ blockSums) {
    __shared__ int sdata[SCAN_B];
    int t = threadIdx.x;
    int base = blockIdx.x * SCAN_TILE + t * 4;
    int v0 = 0, v1 = 0, v2 = 0, v3 = 0;
    if (base + 3 < n) {
        int4 c = *(const int4*)(counts + base);
        v0 = c.x; v1 = c.y; v2 = c.z; v3 = c.w;
    } else {
        if (base     < n) v0 = counts[base];
        if (base + 1 < n) v1 = counts[base + 1];
        if (base + 2 < n) v2 = counts[base + 2];
        if (base + 3 < n) v3 = counts[base + 3];
    }
    int s = v0 + v1 + v2 + v3;
    sdata[t] = s;
    __syncthreads();
    for (int off = 1; off < SCAN_B; off <<= 1) {
        int x = (t >= off) ? sdata[t - off] : 0;
        __syncthreads();
        sdata[t] += x;
        __syncthreads();
    }
    int excl = sdata[t] - s;
    if (t == SCAN_B - 1) blockSums[blockIdx.x] = sdata[t];
    if (base     < n) row_ptr[base]     = excl;
    if (base + 1 < n) row_ptr[base + 1] = excl + v0;
    if (base + 2 < n) row_ptr[base + 2] = excl + v0 + v1;
    if (base + 3 < n) row_ptr[base + 3] = excl + v0 + v1 + v2;
}

__global__ void scan2_kernel(int* __restrict__ blockSums, int G) {
    if (threadIdx.x == 0 && blockIdx.x == 0) {
        int run = 0;
        for (int i = 0; i < G; ++i) { int v = blockSums[i]; blockSums[i] = run; run += v; }
    }
}

__global__ void scan3_kernel(int* __restrict__ row_ptr,
                             const int* __restrict__ blockSums,
                             int* __restrict__ cursor, int n, int e) {
    int i = blockIdx.x * blockDim.x + threadIdx.x;
    if (i < n) {
        int v = row_ptr[i] + blockSums[i >> 10];
        row_ptr[i] = v;
        cursor[i] = v;
    }
    if (i == 0) row_ptr[n] = e;
}

__global__ void build_kernel(const int* __restrict__ src,
                             const int* __restrict__ dst,
                             const float* __restrict__ ew,
                             const float* __restrict__ dis,
                             int* __restrict__ cursor,
                             int2* __restrict__ pairs, int e) {
    int i = blockIdx.x * blockDim.x + threadIdx.x;
    if (i < e) {
        int s = src[i], c = dst[i];
        float nm = dis[s] * ew[i] * dis[c];
        int pos = atomicAdd(&cursor[c], 1);
        pairs[pos] = make_int2(s, __float_as_int(nm));
    }
}

__global__ void agg_kernel(const int* __restrict__ row_ptr,
                           const int2* __restrict__ pairs,
                           const float* __restrict__ h,
                           const float* __restrict__ dis,
                           const float* __restrict__ b,
                           float* __restrict__ out, int n) {
    int t = threadIdx.x;
    int node = blockIdx.x * 4 + (t >> 6);
    int d = t & 63;
    if (node >= n) return;

    float s0 = dis[node];
    float acc = b[d] + s0 * s0 * h[(size_t)node * D + d];

    int beg = row_ptr[node], end = row_ptr[node + 1];
    #pragma unroll 4
    for (int ee = beg; ee < end; ++ee) {
        int2 p = pairs[ee];
        acc = fmaf(__int_as_float(p.y), h[(size_t)p.x * D + d], acc);
    }
    out[(size_t)node * D + d] = acc;
}

// ===========================================================================
extern "C" void kernel_launch(void* const* d_in, const int* in_sizes, int n_in,
                              void* d_out, int out_size, void* d_ws, size_t ws_size,
                              hipStream_t stream) {
    const float* x  = (const float*)d_in[0];
    const float* ea = (const float*)d_in[1];
    const float* W1 = (const float*)d_in[2];
    const float* b1 = (const float*)d_in[3];
    const float* W2 = (const float*)d_in[4];
    const float* b2 = (const float*)d_in[5];
    const int*   ei = (const int*)d_in[6];

    const int n = in_sizes[0] / D;      // 100000
    const int e = in_sizes[1];          // 1200000
    const int* src = ei;
    const int* dst = ei + e;
    float* out = (float*)d_out;

    const int B = 256;
    dim3 blk(B);
    int gN = (n + B - 1) / B;
    int gE = (e + B - 1) / B;
    int gL   = (n + 3) / 4;             // agg: 4 nodes/block
    int gL32 = (n + 31) / 32;           // linear: 32 nodes/block
    int nchunk  = (e + CHUNK - 1) / CHUNK;
    int nb_used = (n + BSIZE - 1) / BSIZE;

    // ---- partition-path workspace layout (word offsets, 256-word aligned) --
    size_t o = 0;
    auto alloc = [&](size_t words) { size_t r = o; o = (o + words + 255) & ~(size_t)255; return r; };
    size_t off_hist  = alloc((size_t)NBUCKET * nchunk);
    size_t off_ofs   = alloc((size_t)NBUCKET * nchunk);
    size_t off_btot  = alloc(NBUCKET);
    size_t off_bbase = alloc(NBUCKET + 1);
    size_t off_psw   = alloc((size_t)e * 2);
    size_t off_pairs = alloc((size_t)e * 2);
    size_t off_rp    = alloc(n + 1);
    size_t off_dis   = alloc(n);
    size_t off_h1    = alloc((size_t)n * D / 2);   // __half
    size_t off_o1    = alloc((size_t)n * D / 2);   // __half
    size_t need_bytes = o * 4;

    float* ws = (float*)d_ws;

    if (ws_size >= need_bytes && n <= NBUCKET * BSIZE) {
        // ================= PARTITION PATH =================
        int*    hist  = (int*)(ws + off_hist);
        int*    ofs   = (int*)(ws + off_ofs);
        int*    btot  = (int*)(ws + off_btot);
        int*    bbase = (int*)(ws + off_bbase);
        int2*   psw   = (int2*)(ws + off_psw);
        int2*   pairs = (int2*)(ws + off_pairs);
        int*    rp    = (int*)(ws + off_rp);
        float*  dis   = ws + off_dis;
        __half* h1    = (__half*)(ws + off_h1);
        __half* o1    = (__half*)(ws + off_o1);

        part_hist_kernel<<<nchunk, blk, 0, stream>>>(dst, e, nchunk, hist);
        part_scanA_kernel<<<NBUCKET, blk, 0, stream>>>(hist, nchunk, ofs, btot);
        part_scanB_kernel<<<1, dim3(NBUCKET), 0, stream>>>(btot, bbase, e);
        part_scatter_kernel<<<nchunk, blk, 0, stream>>>(src, dst, ea, ofs, bbase, nchunk, e, psw);
        bucket_bin_kernel<<<nb_used, blk, 0, stream>>>(psw, bbase, n, e, pairs, rp, dis);

        // h1' = dis * (x @ W1^T)
        linear_kernel<false, true, float, __half><<<gL32, blk, 0, stream>>>(x, W1, dis, h1, n);
        // o1 = relu(b1 + dis * T1)
        agg_csr_kernel<true, __half><<<gL, blk, 0, stream>>>(rp, pairs, h1, dis, b1, o1, n);
        // h2' = dis * (o1 @ W2^T)   (reuse h1 buffer)
        linear_kernel<false, true, __half, __half><<<gL32, blk, 0, stream>>>(o1, W2, dis, h1, n);
        // out = b2 + dis * T2
        agg_csr_kernel<false, float><<<gL, blk, 0, stream>>>(rp, pairs, h1, dis, b2, out, n);
    } else {
        // ================= CSR FALLBACK (proven R2, fp32) =================
        size_t o2 = 0;
        auto alloc2 = [&](size_t words) { size_t r = o2; o2 = (o2 + words + 255) & ~(size_t)255; return r; };
        float* dis       = ws + alloc2(n);
        int*   row_ptr   = (int*)(ws + alloc2(n + 1));
        int*   cursor    = (int*)(ws + alloc2(n));
        int*   blockSums = (int*)(ws + alloc2(512));
        int2*  pairs     = (int2*)(ws + alloc2((size_t)e * 2));
        float* h         = ws + alloc2((size_t)n * D);
        float* out1      = ws + alloc2((size_t)n * D);
        int*   counts    = cursor;
        int G = (n + SCAN_TILE - 1) / SCAN_TILE;

        init_deg_counts_kernel<<<gN, blk, 0, stream>>>(dis, counts, n);
        edge_hist_kernel<<<gE, blk, 0, stream>>>(dst, ea, dis, counts, e);
        finish_dis_kernel<<<gN, blk, 0, stream>>>(dis, n);
        scan1_kernel<<<G, blk, 0, stream>>>(counts, n, row_ptr, blockSums);
        scan2_kernel<<<1, blk, 0, stream>>>(blockSums, G);
        scan3_kernel<<<gN, blk, 0, stream>>>(row_ptr, blockSums, cursor, n, e);
        build_kernel<<<gE, blk, 0, stream>>>(src, dst, ea, dis, cursor, pairs, e);

        linear_kernel<false, false, float, float><<<gL32, blk, 0, stream>>>(x, W1, nullptr, h, n);
        agg_kernel<<<gL, blk, 0, stream>>>(row_ptr, pairs, h, dis, b1, out1, n);

        linear_kernel<true, false, float, float><<<gL32, blk, 0, stream>>>(out1, W2, nullptr, h, n);
        agg_kernel<<<gL, blk, 0, stream>>>(row_ptr, pairs, h, dis, b2, out, n);
    }
}

// Round 12
// 189.133 us; speedup vs baseline: 1.4724x; 1.1806x over previous
//
#include <hip/hip_runtime.h>
#include <hip/hip_fp16.h>

#define D 64
#define CHUNK 4096
#define BSIZE 256          // nodes per bucket (dst >> 8)
#define NBUCKET 512        // covers up to 131072 nodes (src fits in 17 bits)

// ---- load/store helpers (fp32 or fp16 storage, fp32 compute) --------------
static __device__ __forceinline__ float ldf(const float* p)  { return *p; }
static __device__ __forceinline__ float ldf(const __half* p) { return __half2float(*p); }
static __device__ __forceinline__ void  stf(float* p, float v)  { *p = v; }
static __device__ __forceinline__ void  stf(__half* p, float v) { *p = __float2half(v); }

// ===========================================================================
// h = scale * (optional relu)(x) @ W^T   [n,64]x[64,64]; 32 nodes/block
// W column held in registers (64 VGPR); sx k-loop reads are wave-broadcast.
// ===========================================================================
template <bool RELU, bool SCALE, typename IN_T, typename OUT_T>
__global__ void linear_kernel(const IN_T* __restrict__ x,
                              const float* __restrict__ W,
                              const float* __restrict__ dis,
                              OUT_T* __restrict__ h, int n) {
    __shared__ float sW[D * 65];
    __shared__ float sx[4][D];

    int t = threadIdx.x;
    #pragma unroll
    for (int j = 0; j < (D * D) / 256; ++j) {
        int idx = t + j * 256;
        sW[(idx >> 6) * 65 + (idx & 63)] = W[idx];
    }
    __syncthreads();

    int r = t >> 6, d = t & 63;

    // copy my output dim's W column into registers (once per block)
    float wreg[D];
    #pragma unroll
    for (int k = 0; k < D; ++k) wreg[k] = sW[d * 65 + k];

    int node0 = blockIdx.x * 32;
    for (int g = 0; g < 8; ++g) {
        int node = node0 + g * 4 + r;
        __syncthreads();                   // sx safe to overwrite
        float v = (node < n) ? ldf(&x[(size_t)node * D + d]) : 0.0f;
        if (RELU) v = fmaxf(v, 0.0f);
        sx[r][d] = v;
        __syncthreads();
        if (node < n) {
            float acc = 0.0f;
            #pragma unroll
            for (int k = 0; k < D; k += 4) {
                float4 xv = *(const float4*)&sx[r][k];   // wave-broadcast read
                acc = fmaf(xv.x, wreg[k],     acc);
                acc = fmaf(xv.y, wreg[k + 1], acc);
                acc = fmaf(xv.z, wreg[k + 2], acc);
                acc = fmaf(xv.w, wreg[k + 3], acc);
            }
            if (SCALE) acc *= dis[node];
            stf(&h[(size_t)node * D + d], acc);
        }
    }
}

// ===========================================================================
// PARTITION PATH
// ===========================================================================
// A: per-chunk bucket histogram (LDS atomics only); 512 buckets, 256 threads
__global__ void part_hist_kernel(const int* __restrict__ dst, int e,
                                 int nchunk, int* __restrict__ hist) {
    __shared__ int cnt[NBUCKET];
    int t = threadIdx.x;
    cnt[t] = 0; cnt[t + 256] = 0;
    __syncthreads();
    int base = blockIdx.x * CHUNK;
    int end = min(base + CHUNK, e);
    int nv = (end - base) >> 2;
    for (int g = t; g < nv; g += 256) {
        int4 c4 = *(const int4*)(dst + base + g * 4);
        atomicAdd(&cnt[c4.x >> 8], 1);
        atomicAdd(&cnt[c4.y >> 8], 1);
        atomicAdd(&cnt[c4.z >> 8], 1);
        atomicAdd(&cnt[c4.w >> 8], 1);
    }
    if (t < ((end - base) & 3))
        atomicAdd(&cnt[dst[base + nv * 4 + t] >> 8], 1);
    __syncthreads();
    hist[(size_t)t * nchunk + blockIdx.x] = cnt[t];
    hist[(size_t)(t + 256) * nchunk + blockIdx.x] = cnt[t + 256];
}

// B1: per-bucket exclusive scan over its chunk counts (one block per bucket)
__global__ void part_scanA_kernel(const int* __restrict__ hist, int nchunk,
                                  int* __restrict__ ofs,
                                  int* __restrict__ btot) {
    __shared__ int sd[256];
    int b = blockIdx.x, t = threadIdx.x;
    int carry = 0;
    for (int base = 0; base < nchunk; base += 256) {
        int c = base + t;
        int v = (c < nchunk) ? hist[(size_t)b * nchunk + c] : 0;
        sd[t] = v;
        __syncthreads();
        for (int off = 1; off < 256; off <<= 1) {
            int x = (t >= off) ? sd[t - off] : 0;
            __syncthreads();
            sd[t] += x;
            __syncthreads();
        }
        if (c < nchunk) ofs[(size_t)b * nchunk + c] = carry + sd[t] - v;
        carry += sd[255];
        __syncthreads();
    }
    if (t == 0) btot[b] = carry;
}

// B2: scan NBUCKET totals -> bucketBase (single block of NBUCKET threads)
__global__ void part_scanB_kernel(const int* __restrict__ btot,
                                  int* __restrict__ bucketBase, int e) {
    __shared__ int sd[NBUCKET];
    int t = threadIdx.x;
    int v = btot[t];
    sd[t] = v;
    __syncthreads();
    for (int off = 1; off < NBUCKET; off <<= 1) {
        int x = (t >= off) ? sd[t - off] : 0;
        __syncthreads();
        sd[t] += x;
        __syncthreads();
    }
    bucketBase[t] = sd[t] - v;
    if (t == NBUCKET - 1) bucketBase[NBUCKET] = e;
}

// C: scatter edges into bucket-contiguous regions; pack (src | dlow<<17, ew)
__global__ void part_scatter_kernel(const int* __restrict__ src,
                                    const int* __restrict__ dst,
                                    const float* __restrict__ ew,
                                    const int* __restrict__ ofs,
                                    const int* __restrict__ bucketBase,
                                    int nchunk, int e,
                                    int2* __restrict__ psw) {
    __shared__ int cur[NBUCKET];
    int t = threadIdx.x;
    cur[t]       = bucketBase[t]       + ofs[(size_t)t * nchunk + blockIdx.x];
    cur[t + 256] = bucketBase[t + 256] + ofs[(size_t)(t + 256) * nchunk + blockIdx.x];
    __syncthreads();
    int base = blockIdx.x * CHUNK;
    int end = min(base + CHUNK, e);
    int nv = (end - base) >> 2;
    for (int g = t; g < nv; g += 256) {
        int i = base + g * 4;
        int4   c4 = *(const int4*)(dst + i);
        int4   s4 = *(const int4*)(src + i);
        float4 w4 = *(const float4*)(ew + i);
        int p0 = atomicAdd(&cur[c4.x >> 8], 1);
        int p1 = atomicAdd(&cur[c4.y >> 8], 1);
        int p2 = atomicAdd(&cur[c4.z >> 8], 1);
        int p3 = atomicAdd(&cur[c4.w >> 8], 1);
        psw[p0] = make_int2(s4.x | ((c4.x & 255) << 17), __float_as_int(w4.x));
        psw[p1] = make_int2(s4.y | ((c4.y & 255) << 17), __float_as_int(w4.y));
        psw[p2] = make_int2(s4.z | ((c4.z & 255) << 17), __float_as_int(w4.z));
        psw[p3] = make_int2(s4.w | ((c4.w & 255) << 17), __float_as_int(w4.w));
    }
    if (t < ((end - base) & 3)) {
        int k = base + nv * 4 + t;
        int c = dst[k];
        int p = atomicAdd(&cur[c >> 8], 1);
        psw[p] = make_int2(src[k] | ((c & 255) << 17), __float_as_int(ew[k]));
    }
}

// D: per-bucket binning -> CSR pairs (raw ew), row_ptr, dis
__global__ void bucket_bin_kernel(const int2* __restrict__ psw,
                                  const int* __restrict__ bucketBase,
                                  int n, int e,
                                  int2* __restrict__ pairs,
                                  int* __restrict__ row_ptr,
                                  float* __restrict__ dis) {
    __shared__ int   cnt[BSIZE];
    __shared__ float fdeg[BSIZE];
    __shared__ int   sc[BSIZE];

    int t = threadIdx.x;
    int b = blockIdx.x;
    int node0 = b * BSIZE;
    int ebeg = bucketBase[b], eend = bucketBase[b + 1];

    cnt[t] = 0;
    fdeg[t] = 0.0f;
    __syncthreads();

    // pass 1: node counts + weighted degree (LDS atomics)
    for (int i = ebeg + t; i < eend; i += 256) {
        int2 sw = psw[i];
        int c = sw.x >> 17;
        atomicAdd(&cnt[c], 1);
        atomicAdd(&fdeg[c], __int_as_float(sw.y));
    }
    __syncthreads();

    // exclusive scan of 256 counts
    int v = cnt[t];
    sc[t] = v;
    __syncthreads();
    for (int off = 1; off < 256; off <<= 1) {
        int x = (t >= off) ? sc[t - off] : 0;
        __syncthreads();
        sc[t] += x;
        __syncthreads();
    }
    int excl = sc[t] - v;

    int node = node0 + t;
    if (node < n) {
        row_ptr[node] = ebeg + excl;
        float dg = 1.0f + fdeg[t];                 // self-loop weight 1
        dis[node] = (dg > 0.0f) ? rsqrtf(fmaxf(dg, 1e-30f)) : 0.0f;
    }
    if (t == 0 && node0 < n && node0 + BSIZE >= n) row_ptr[n] = e;
    __syncthreads();
    cnt[t] = excl;                                 // cursor
    __syncthreads();

    // pass 2: place pairs (raw ew)
    for (int i = ebeg + t; i < eend; i += 256) {
        int2 sw = psw[i];
        int c = sw.x >> 17;
        int pos = atomicAdd(&cnt[c], 1);
        pairs[ebeg + pos] = make_int2(sw.x & 0x1FFFF, sw.y);
    }
}

// ===========================================================================
// agg over h' (= dis*h):  T = h'[i] + sum_j ew_j*h'[src_j]
// out[i] = (RELU?) relu(bias + dis[i]*T) : bias + dis[i]*T
// wave = node; 4 quarter-waves process 4 consecutive edges concurrently;
// lane covers 4 dims (2x half2, 8B) -> 16 lanes span the 128B row.
// ===========================================================================
template <bool RELU, typename OUT_T>
__global__ void agg_csr_kernel(const int* __restrict__ row_ptr,
                               const int2* __restrict__ pairs,
                               const __half* __restrict__ h,
                               const float* __restrict__ dis,
                               const float* __restrict__ bias,
                               OUT_T* __restrict__ out, int n) {
    int t = threadIdx.x;
    int node = blockIdx.x * 4 + (t >> 6);
    int lane = t & 63, q = lane >> 4, sub = lane & 15;
    if (node >= n) return;

    float4 acc = make_float4(0.0f, 0.0f, 0.0f, 0.0f);
    if (q == 0) {
        float2 raw = ((const float2*)(h + (size_t)node * D))[sub];
        float2 a = __half22float2(*(const __half2*)&raw.x);
        float2 b = __half22float2(*(const __half2*)&raw.y);
        acc = make_float4(a.x, a.y, b.x, b.y);
    }
    int beg = row_ptr[node], end = row_ptr[node + 1];
    #pragma unroll 2
    for (int j = beg + q; j < end; j += 4) {
        int2 p = pairs[j];                 // 4 quarters read 4 consecutive pairs
        float w = __int_as_float(p.y);
        float2 raw = ((const float2*)(h + (size_t)p.x * D))[sub];
        float2 a = __half22float2(*(const __half2*)&raw.x);
        float2 b = __half22float2(*(const __half2*)&raw.y);
        acc.x = fmaf(w, a.x, acc.x);
        acc.y = fmaf(w, a.y, acc.y);
        acc.z = fmaf(w, b.x, acc.z);
        acc.w = fmaf(w, b.y, acc.w);
    }
    // combine the four quarters
    acc.x += __shfl_xor(acc.x, 16, 64);
    acc.y += __shfl_xor(acc.y, 16, 64);
    acc.z += __shfl_xor(acc.z, 16, 64);
    acc.w += __shfl_xor(acc.w, 16, 64);
    acc.x += __shfl_xor(acc.x, 32, 64);
    acc.y += __shfl_xor(acc.y, 32, 64);
    acc.z += __shfl_xor(acc.z, 32, 64);
    acc.w += __shfl_xor(acc.w, 32, 64);

    if (q == 0) {
        float s0 = dis[node];
        float4 bb = ((const float4*)bias)[sub];
        float o0 = fmaf(s0, acc.x, bb.x);
        float o1 = fmaf(s0, acc.y, bb.y);
        float o2 = fmaf(s0, acc.z, bb.z);
        float o3 = fmaf(s0, acc.w, bb.w);
        if (RELU) {
            o0 = fmaxf(o0, 0.0f); o1 = fmaxf(o1, 0.0f);
            o2 = fmaxf(o2, 0.0f); o3 = fmaxf(o3, 0.0f);
        }
        if constexpr (sizeof(OUT_T) == 2) {
            __half2 r0 = __float22half2_rn(make_float2(o0, o1));
            __half2 r1 = __float22half2_rn(make_float2(o2, o3));
            uint2 u = make_uint2(*(unsigned int*)&r0, *(unsigned int*)&r1);
            ((uint2*)(out + (size_t)node * D))[sub] = u;
        } else {
            ((float4*)(out + (size_t)node * D))[sub] = make_float4(o0, o1, o2, o3);
        }
    }
}

// ===========================================================================
// CSR FALLBACK PATH (proven R2 code, fp32) — used only if ws/n don't fit
// ===========================================================================
__global__ void init_deg_counts_kernel(float* __restrict__ deg,
                                       int* __restrict__ counts, int n) {
    int i = blockIdx.x * blockDim.x + threadIdx.x;
    if (i < n) { deg[i] = 1.0f; counts[i] = 0; }
}

__global__ void edge_hist_kernel(const int* __restrict__ dst,
                                 const float* __restrict__ ew,
                                 float* __restrict__ deg,
                                 int* __restrict__ counts, int e) {
    int i = blockIdx.x * blockDim.x + threadIdx.x;
    if (i < e) {
        int c = dst[i];
        atomicAdd(&deg[c], ew[i]);
        atomicAdd(&counts[c], 1);
    }
}

__global__ void finish_dis_kernel(float* __restrict__ deg, int n) {
    int i = blockIdx.x * blockDim.x + threadIdx.x;
    if (i < n) {
        float d = deg[i];
        deg[i] = (d > 0.0f) ? rsqrtf(fmaxf(d, 1e-30f)) : 0.0f;
    }
}

#define SCAN_B 256
#define SCAN_TILE 1024

__global__ void scan1_kernel(const int* __restrict__ counts, int n,
                             int* __restrict__ row_ptr,
                             int* __restrict__ blockSums) {
    __shared__ int sdata[SCAN_B];
    int t = threadIdx.x;
    int base = blockIdx.x * SCAN_TILE + t * 4;
    int v0 = 0, v1 = 0, v2 = 0, v3 = 0;
    if (base + 3 < n) {
        int4 c = *(const int4*)(counts + base);
        v0 = c.x; v1 = c.y; v2 = c.z; v3 = c.w;
    } else {
        if (base     < n) v0 = counts[base];
        if (base + 1 < n) v1 = counts[base + 1];
        if (base + 2 < n) v2 = counts[base + 2];
        if (base + 3 < n) v3 = counts[base + 3];
    }
    int s = v0 + v1 + v2 + v3;
    sdata[t] = s;
    __syncthreads();
    for (int off = 1; off < SCAN_B; off <<= 1) {
        int x = (t >= off) ? sdata[t - off] : 0;
        __syncthreads();
        sdata[t] += x;
        __syncthreads();
    }
    int excl = sdata[t] - s;
    if (t == SCAN_B - 1) blockSums[blockIdx.x] = sdata[t];
    if (base     < n) row_ptr[base]     = excl;
    if (base + 1 < n) row_ptr[base + 1] = excl + v0;
    if (base + 2 < n) row_ptr[base + 2] = excl + v0 + v1;
    if (base + 3 < n) row_ptr[base + 3] = excl + v0 + v1 + v2;
}

__global__ void scan2_kernel(int* __restrict__ blockSums, int G) {
    if (threadIdx.x == 0 && blockIdx.x == 0) {
        int run = 0;
        for (int i = 0; i < G; ++i) { int v = blockSums[i]; blockSums[i] = run; run += v; }
    }
}

__global__ void scan3_kernel(int* __restrict__ row_ptr,
                             const int* __restrict__ blockSums,
                             int* __restrict__ cursor, int n, int e) {
    int i = blockIdx.x * blockDim.x + threadIdx.x;
    if (i < n) {
        int v = row_ptr[i] + blockSums[i >> 10];
        row_ptr[i] = v;
        cursor[i] = v;
    }
    if (i == 0) row_ptr[n] = e;
}

__global__ void build_kernel(const int* __restrict__ src,
                             const int* __restrict__ dst,
                             const float* __restrict__ ew,
                             const float* __restrict__ dis,
                             int* __restrict__ cursor,
                             int2* __restrict__ pairs, int e) {
    int i = blockIdx.x * blockDim.x + threadIdx.x;
    if (i < e) {
        int s = src[i], c = dst[i];
        float nm = dis[s] * ew[i] * dis[c];
        int pos = atomicAdd(&cursor[c], 1);
        pairs[pos] = make_int2(s, __float_as_int(nm));
    }
}

__global__ void agg_kernel(const int* __restrict__ row_ptr,
                           const int2* __restrict__ pairs,
                           const float* __restrict__ h,
                           const float* __restrict__ dis,
                           const float* __restrict__ b,
                           float* __restrict__ out, int n) {
    int t = threadIdx.x;
    int node = blockIdx.x * 4 + (t >> 6);
    int d = t & 63;
    if (node >= n) return;

    float s0 = dis[node];
    float acc = b[d] + s0 * s0 * h[(size_t)node * D + d];

    int beg = row_ptr[node], end = row_ptr[node + 1];
    #pragma unroll 4
    for (int ee = beg; ee < end; ++ee) {
        int2 p = pairs[ee];
        acc = fmaf(__int_as_float(p.y), h[(size_t)p.x * D + d], acc);
    }
    out[(size_t)node * D + d] = acc;
}

// ===========================================================================
extern "C" void kernel_launch(void* const* d_in, const int* in_sizes, int n_in,
                              void* d_out, int out_size, void* d_ws, size_t ws_size,
                              hipStream_t stream) {
    const float* x  = (const float*)d_in[0];
    const float* ea = (const float*)d_in[1];
    const float* W1 = (const float*)d_in[2];
    const float* b1 = (const float*)d_in[3];
    const float* W2 = (const float*)d_in[4];
    const float* b2 = (const float*)d_in[5];
    const int*   ei = (const int*)d_in[6];

    const int n = in_sizes[0] / D;      // 100000
    const int e = in_sizes[1];          // 1200000
    const int* src = ei;
    const int* dst = ei + e;
    float* out = (float*)d_out;

    const int B = 256;
    dim3 blk(B);
    int gN = (n + B - 1) / B;
    int gE = (e + B - 1) / B;
    int gL   = (n + 3) / 4;             // agg: 4 nodes/block
    int gL32 = (n + 31) / 32;           // linear: 32 nodes/block
    int nchunk  = (e + CHUNK - 1) / CHUNK;
    int nb_used = (n + BSIZE - 1) / BSIZE;

    // ---- partition-path workspace layout (word offsets, 256-word aligned) --
    size_t o = 0;
    auto alloc = [&](size_t words) { size_t r = o; o = (o + words + 255) & ~(size_t)255; return r; };
    size_t off_hist  = alloc((size_t)NBUCKET * nchunk);
    size_t off_ofs   = alloc((size_t)NBUCKET * nchunk);
    size_t off_btot  = alloc(NBUCKET);
    size_t off_bbase = alloc(NBUCKET + 1);
    size_t off_psw   = alloc((size_t)e * 2);
    size_t off_pairs = alloc((size_t)e * 2);
    size_t off_rp    = alloc(n + 1);
    size_t off_dis   = alloc(n);
    size_t off_h1    = alloc((size_t)n * D / 2);   // __half
    size_t off_o1    = alloc((size_t)n * D / 2);   // __half
    size_t need_bytes = o * 4;

    float* ws = (float*)d_ws;

    if (ws_size >= need_bytes && n <= NBUCKET * BSIZE) {
        // ================= PARTITION PATH =================
        int*    hist  = (int*)(ws + off_hist);
        int*    ofs   = (int*)(ws + off_ofs);
        int*    btot  = (int*)(ws + off_btot);
        int*    bbase = (int*)(ws + off_bbase);
        int2*   psw   = (int2*)(ws + off_psw);
        int2*   pairs = (int2*)(ws + off_pairs);
        int*    rp    = (int*)(ws + off_rp);
        float*  dis   = ws + off_dis;
        __half* h1    = (__half*)(ws + off_h1);
        __half* o1    = (__half*)(ws + off_o1);

        part_hist_kernel<<<nchunk, blk, 0, stream>>>(dst, e, nchunk, hist);
        part_scanA_kernel<<<NBUCKET, blk, 0, stream>>>(hist, nchunk, ofs, btot);
        part_scanB_kernel<<<1, dim3(NBUCKET), 0, stream>>>(btot, bbase, e);
        part_scatter_kernel<<<nchunk, blk, 0, stream>>>(src, dst, ea, ofs, bbase, nchunk, e, psw);
        bucket_bin_kernel<<<nb_used, blk, 0, stream>>>(psw, bbase, n, e, pairs, rp, dis);

        // h1' = dis * (x @ W1^T)
        linear_kernel<false, true, float, __half><<<gL32, blk, 0, stream>>>(x, W1, dis, h1, n);
        // o1 = relu(b1 + dis * T1)
        agg_csr_kernel<true, __half><<<gL, blk, 0, stream>>>(rp, pairs, h1, dis, b1, o1, n);
        // h2' = dis * (o1 @ W2^T)   (reuse h1 buffer)
        linear_kernel<false, true, __half, __half><<<gL32, blk, 0, stream>>>(o1, W2, dis, h1, n);
        // out = b2 + dis * T2
        agg_csr_kernel<false, float><<<gL, blk, 0, stream>>>(rp, pairs, h1, dis, b2, out, n);
    } else {
        // ================= CSR FALLBACK (proven R2, fp32) =================
        size_t o2 = 0;
        auto alloc2 = [&](size_t words) { size_t r = o2; o2 = (o2 + words + 255) & ~(size_t)255; return r; };
        float* dis       = ws + alloc2(n);
        int*   row_ptr   = (int*)(ws + alloc2(n + 1));
        int*   cursor    = (int*)(ws + alloc2(n));
        int*   blockSums = (int*)(ws + alloc2(512));
        int2*  pairs     = (int2*)(ws + alloc2((size_t)e * 2));
        float* h         = ws + alloc2((size_t)n * D);
        float* out1      = ws + alloc2((size_t)n * D);
        int*   counts    = cursor;
        int G = (n + SCAN_TILE - 1) / SCAN_TILE;

        init_deg_counts_kernel<<<gN, blk, 0, stream>>>(dis, counts, n);
        edge_hist_kernel<<<gE, blk, 0, stream>>>(dst, ea, dis, counts, e);
        finish_dis_kernel<<<gN, blk, 0, stream>>>(dis, n);
        scan1_kernel<<<G, blk, 0, stream>>>(counts, n, row_ptr, blockSums);
        scan2_kernel<<<1, blk, 0, stream>>>(blockSums, G);
        scan3_kernel<<<gN, blk, 0, stream>>>(row_ptr, blockSums, cursor, n, e);
        build_kernel<<<gE, blk, 0, stream>>>(src, dst, ea, dis, cursor, pairs, e);

        linear_kernel<false, false, float, float><<<gL32, blk, 0, stream>>>(x, W1, nullptr, h, n);
        agg_kernel<<<gL, blk, 0, stream>>>(row_ptr, pairs, h, dis, b1, out1, n);

        linear_kernel<true, false, float, float><<<gL32, blk, 0, stream>>>(out1, W2, nullptr, h, n);
        agg_kernel<<<gL, blk, 0, stream>>>(row_ptr, pairs, h, dis, b2, out, n);
    }
}

// Round 13
// 186.863 us; speedup vs baseline: 1.4903x; 1.0121x over previous
//
#include <hip/hip_runtime.h>
#include <hip/hip_fp16.h>

#define D 64
#define CHUNK 8192
#define BSIZE 256          // nodes per bucket (dst >> 8)
#define NBUCKET 512        // covers up to 131072 nodes (src fits in 17 bits)
#define PTH 512            // partition kernels' block size

// ---- load/store helpers (fp32 or fp16 storage, fp32 compute) --------------
static __device__ __forceinline__ float ldf(const float* p)  { return *p; }
static __device__ __forceinline__ float ldf(const __half* p) { return __half2float(*p); }
static __device__ __forceinline__ void  stf(float* p, float v)  { *p = v; }
static __device__ __forceinline__ void  stf(__half* p, float v) { *p = __float2half(v); }

// ===========================================================================
// h = scale * (optional relu)(x) @ W^T   [n,64]x[64,64]; 32 nodes/block
// W column held in registers (64 VGPR); sx k-loop reads are wave-broadcast.
// ===========================================================================
template <bool RELU, bool SCALE, typename IN_T, typename OUT_T>
__global__ void linear_kernel(const IN_T* __restrict__ x,
                              const float* __restrict__ W,
                              const float* __restrict__ dis,
                              OUT_T* __restrict__ h, int n) {
    __shared__ float sW[D * 65];
    __shared__ float sx[4][D];

    int t = threadIdx.x;
    #pragma unroll
    for (int j = 0; j < (D * D) / 256; ++j) {
        int idx = t + j * 256;
        sW[(idx >> 6) * 65 + (idx & 63)] = W[idx];
    }
    __syncthreads();

    int r = t >> 6, d = t & 63;

    float wreg[D];
    #pragma unroll
    for (int k = 0; k < D; ++k) wreg[k] = sW[d * 65 + k];

    int node0 = blockIdx.x * 32;
    for (int g = 0; g < 8; ++g) {
        int node = node0 + g * 4 + r;
        __syncthreads();
        float v = (node < n) ? ldf(&x[(size_t)node * D + d]) : 0.0f;
        if (RELU) v = fmaxf(v, 0.0f);
        sx[r][d] = v;
        __syncthreads();
        if (node < n) {
            float acc = 0.0f;
            #pragma unroll
            for (int k = 0; k < D; k += 4) {
                float4 xv = *(const float4*)&sx[r][k];   // wave-broadcast read
                acc = fmaf(xv.x, wreg[k],     acc);
                acc = fmaf(xv.y, wreg[k + 1], acc);
                acc = fmaf(xv.z, wreg[k + 2], acc);
                acc = fmaf(xv.w, wreg[k + 3], acc);
            }
            if (SCALE) acc *= dis[node];
            stf(&h[(size_t)node * D + d], acc);
        }
    }
}

// ===========================================================================
// PARTITION PATH  (512-thread blocks)
// ===========================================================================
// A: per-chunk bucket histogram (LDS atomics only)
__global__ void part_hist_kernel(const int* __restrict__ dst, int e,
                                 int nchunk, int* __restrict__ hist) {
    __shared__ int cnt[NBUCKET];
    int t = threadIdx.x;
    cnt[t] = 0;
    __syncthreads();
    int base = blockIdx.x * CHUNK;
    int end = min(base + CHUNK, e);
    int nv = (end - base) >> 2;
    for (int g = t; g < nv; g += PTH) {
        int4 c4 = *(const int4*)(dst + base + g * 4);
        atomicAdd(&cnt[c4.x >> 8], 1);
        atomicAdd(&cnt[c4.y >> 8], 1);
        atomicAdd(&cnt[c4.z >> 8], 1);
        atomicAdd(&cnt[c4.w >> 8], 1);
    }
    if (t < ((end - base) & 3))
        atomicAdd(&cnt[dst[base + nv * 4 + t] >> 8], 1);
    __syncthreads();
    hist[(size_t)t * nchunk + blockIdx.x] = cnt[t];
}

// B1: per-bucket exclusive scan over its chunk counts (one block per bucket)
__global__ void part_scanA_kernel(const int* __restrict__ hist, int nchunk,
                                  int* __restrict__ ofs,
                                  int* __restrict__ btot) {
    __shared__ int sd[256];
    int b = blockIdx.x, t = threadIdx.x;
    int carry = 0;
    for (int base = 0; base < nchunk; base += 256) {
        int c = base + t;
        int v = (c < nchunk) ? hist[(size_t)b * nchunk + c] : 0;
        sd[t] = v;
        __syncthreads();
        for (int off = 1; off < 256; off <<= 1) {
            int x = (t >= off) ? sd[t - off] : 0;
            __syncthreads();
            sd[t] += x;
            __syncthreads();
        }
        if (c < nchunk) ofs[(size_t)b * nchunk + c] = carry + sd[t] - v;
        carry += sd[255];
        __syncthreads();
    }
    if (t == 0) btot[b] = carry;
}

// B2: scan NBUCKET totals -> bucketBase (single block of NBUCKET threads)
__global__ void part_scanB_kernel(const int* __restrict__ btot,
                                  int* __restrict__ bucketBase, int e) {
    __shared__ int sd[NBUCKET];
    int t = threadIdx.x;
    int v = btot[t];
    sd[t] = v;
    __syncthreads();
    for (int off = 1; off < NBUCKET; off <<= 1) {
        int x = (t >= off) ? sd[t - off] : 0;
        __syncthreads();
        sd[t] += x;
        __syncthreads();
    }
    bucketBase[t] = sd[t] - v;
    if (t == NBUCKET - 1) bucketBase[NBUCKET] = e;
}

// C: scatter edges into bucket-contiguous regions; pack (src | dlow<<17, ew)
__global__ void part_scatter_kernel(const int* __restrict__ src,
                                    const int* __restrict__ dst,
                                    const float* __restrict__ ew,
                                    const int* __restrict__ ofs,
                                    const int* __restrict__ bucketBase,
                                    int nchunk, int e,
                                    int2* __restrict__ psw) {
    __shared__ int cur[NBUCKET];
    int t = threadIdx.x;
    cur[t] = bucketBase[t] + ofs[(size_t)t * nchunk + blockIdx.x];
    __syncthreads();
    int base = blockIdx.x * CHUNK;
    int end = min(base + CHUNK, e);
    int nv = (end - base) >> 2;
    for (int g = t; g < nv; g += PTH) {
        int i = base + g * 4;
        int4   c4 = *(const int4*)(dst + i);
        int4   s4 = *(const int4*)(src + i);
        float4 w4 = *(const float4*)(ew + i);
        int p0 = atomicAdd(&cur[c4.x >> 8], 1);
        int p1 = atomicAdd(&cur[c4.y >> 8], 1);
        int p2 = atomicAdd(&cur[c4.z >> 8], 1);
        int p3 = atomicAdd(&cur[c4.w >> 8], 1);
        psw[p0] = make_int2(s4.x | ((c4.x & 255) << 17), __float_as_int(w4.x));
        psw[p1] = make_int2(s4.y | ((c4.y & 255) << 17), __float_as_int(w4.y));
        psw[p2] = make_int2(s4.z | ((c4.z & 255) << 17), __float_as_int(w4.z));
        psw[p3] = make_int2(s4.w | ((c4.w & 255) << 17), __float_as_int(w4.w));
    }
    if (t < ((end - base) & 3)) {
        int k = base + nv * 4 + t;
        int c = dst[k];
        int p = atomicAdd(&cur[c >> 8], 1);
        psw[p] = make_int2(src[k] | ((c & 255) << 17), __float_as_int(ew[k]));
    }
}

// D: per-bucket binning -> CSR pairs (raw ew), row_ptr, dis; 512 threads
__global__ void bucket_bin_kernel(const int2* __restrict__ psw,
                                  const int* __restrict__ bucketBase,
                                  int n, int e,
                                  int2* __restrict__ pairs,
                                  int* __restrict__ row_ptr,
                                  float* __restrict__ dis) {
    __shared__ int   cnt[BSIZE];
    __shared__ float fdeg[BSIZE];
    __shared__ int   sc[BSIZE];

    int t = threadIdx.x;
    int b = blockIdx.x;
    int node0 = b * BSIZE;
    int ebeg = bucketBase[b], eend = bucketBase[b + 1];

    if (t < BSIZE) { cnt[t] = 0; fdeg[t] = 0.0f; }
    __syncthreads();

    // pass 1: node counts + weighted degree (LDS atomics)
    for (int i = ebeg + t; i < eend; i += PTH) {
        int2 sw = psw[i];
        int c = sw.x >> 17;
        atomicAdd(&cnt[c], 1);
        atomicAdd(&fdeg[c], __int_as_float(sw.y));
    }
    __syncthreads();

    // exclusive scan of 256 counts (first 256 threads active, uniform barriers)
    int v = (t < BSIZE) ? cnt[t] : 0;
    if (t < BSIZE) sc[t] = v;
    __syncthreads();
    for (int off = 1; off < BSIZE; off <<= 1) {
        int x = (t < BSIZE && t >= off) ? sc[t - off] : 0;
        __syncthreads();
        if (t < BSIZE) sc[t] += x;
        __syncthreads();
    }
    int excl = (t < BSIZE) ? sc[t] - v : 0;

    if (t < BSIZE) {
        int node = node0 + t;
        if (node < n) {
            row_ptr[node] = ebeg + excl;
            float dg = 1.0f + fdeg[t];             // self-loop weight 1
            dis[node] = (dg > 0.0f) ? rsqrtf(fmaxf(dg, 1e-30f)) : 0.0f;
        }
    }
    if (t == 0 && node0 < n && node0 + BSIZE >= n) row_ptr[n] = e;
    __syncthreads();
    if (t < BSIZE) cnt[t] = excl;                  // cursor
    __syncthreads();

    // pass 2: place pairs (raw ew)
    for (int i = ebeg + t; i < eend; i += PTH) {
        int2 sw = psw[i];
        int c = sw.x >> 17;
        int pos = atomicAdd(&cnt[c], 1);
        pairs[ebeg + pos] = make_int2(sw.x & 0x1FFFF, sw.y);
    }
}

// ===========================================================================
// agg over h' (= dis*h):  T = h'[i] + sum_j ew_j*h'[src_j]
// out[i] = (RELU?) relu(bias + dis[i]*T) : bias + dis[i]*T
// wave = node; 4 quarter-waves process 4 consecutive edges concurrently;
// lane covers 4 dims (2x half2, 8B) -> 16 lanes span the 128B row.
// ===========================================================================
template <bool RELU, typename OUT_T>
__global__ void agg_csr_kernel(const int* __restrict__ row_ptr,
                               const int2* __restrict__ pairs,
                               const __half* __restrict__ h,
                               const float* __restrict__ dis,
                               const float* __restrict__ bias,
                               OUT_T* __restrict__ out, int n) {
    int t = threadIdx.x;
    int node = blockIdx.x * 4 + (t >> 6);
    int lane = t & 63, q = lane >> 4, sub = lane & 15;
    if (node >= n) return;

    float4 acc = make_float4(0.0f, 0.0f, 0.0f, 0.0f);
    if (q == 0) {
        float2 raw = ((const float2*)(h + (size_t)node * D))[sub];
        float2 a = __half22float2(*(const __half2*)&raw.x);
        float2 b = __half22float2(*(const __half2*)&raw.y);
        acc = make_float4(a.x, a.y, b.x, b.y);
    }
    int beg = row_ptr[node], end = row_ptr[node + 1];
    #pragma unroll 2
    for (int j = beg + q; j < end; j += 4) {
        int2 p = pairs[j];                 // 4 quarters read 4 consecutive pairs
        float w = __int_as_float(p.y);
        float2 raw = ((const float2*)(h + (size_t)p.x * D))[sub];
        float2 a = __half22float2(*(const __half2*)&raw.x);
        float2 b = __half22float2(*(const __half2*)&raw.y);
        acc.x = fmaf(w, a.x, acc.x);
        acc.y = fmaf(w, a.y, acc.y);
        acc.z = fmaf(w, b.x, acc.z);
        acc.w = fmaf(w, b.y, acc.w);
    }
    // combine the four quarters
    acc.x += __shfl_xor(acc.x, 16, 64);
    acc.y += __shfl_xor(acc.y, 16, 64);
    acc.z += __shfl_xor(acc.z, 16, 64);
    acc.w += __shfl_xor(acc.w, 16, 64);
    acc.x += __shfl_xor(acc.x, 32, 64);
    acc.y += __shfl_xor(acc.y, 32, 64);
    acc.z += __shfl_xor(acc.z, 32, 64);
    acc.w += __shfl_xor(acc.w, 32, 64);

    if (q == 0) {
        float s0 = dis[node];
        float4 bb = ((const float4*)bias)[sub];
        float o0 = fmaf(s0, acc.x, bb.x);
        float o1 = fmaf(s0, acc.y, bb.y);
        float o2 = fmaf(s0, acc.z, bb.z);
        float o3 = fmaf(s0, acc.w, bb.w);
        if (RELU) {
            o0 = fmaxf(o0, 0.0f); o1 = fmaxf(o1, 0.0f);
            o2 = fmaxf(o2, 0.0f); o3 = fmaxf(o3, 0.0f);
        }
        if constexpr (sizeof(OUT_T) == 2) {
            __half2 r0 = __float22half2_rn(make_float2(o0, o1));
            __half2 r1 = __float22half2_rn(make_float2(o2, o3));
            uint2 u = make_uint2(*(unsigned int*)&r0, *(unsigned int*)&r1);
            ((uint2*)(out + (size_t)node * D))[sub] = u;
        } else {
            ((float4*)(out + (size_t)node * D))[sub] = make_float4(o0, o1, o2, o3);
        }
    }
}

// ===========================================================================
// CSR FALLBACK PATH (proven R2 code, fp32) — used only if ws/n don't fit
// ===========================================================================
__global__ void init_deg_counts_kernel(float* __restrict__ deg,
                                       int* __restrict__ counts, int n) {
    int i = blockIdx.x * blockDim.x + threadIdx.x;
    if (i < n) { deg[i] = 1.0f; counts[i] = 0; }
}

__global__ void edge_hist_kernel(const int* __restrict__ dst,
                                 const float* __restrict__ ew,
                                 float* __restrict__ deg,
                                 int* __restrict__ counts, int e) {
    int i = blockIdx.x * blockDim.x + threadIdx.x;
    if (i < e) {
        int c = dst[i];
        atomicAdd(&deg[c], ew[i]);
        atomicAdd(&counts[c], 1);
    }
}

__global__ void finish_dis_kernel(float* __restrict__ deg, int n) {
    int i = blockIdx.x * blockDim.x + threadIdx.x;
    if (i < n) {
        float d = deg[i];
        deg[i] = (d > 0.0f) ? rsqrtf(fmaxf(d, 1e-30f)) : 0.0f;
    }
}

#define SCAN_B 256
#define SCAN_TILE 1024

__global__ void scan1_kernel(const int* __restrict__ counts, int n,
                             int* __restrict__ row_ptr,
                             int* __restrict__ blockSums) {
    __shared__ int sdata[SCAN_B];
    int t = threadIdx.x;
    int base = blockIdx.x * SCAN_TILE + t * 4;
    int v0 = 0, v1 = 0, v2 = 0, v3 = 0;
    if (base + 3 < n) {
        int4 c = *(const int4*)(counts + base);
        v0 = c.x; v1 = c.y; v2 = c.z; v3 = c.w;
    } else {
        if (base     < n) v0 = counts[base];
        if (base + 1 < n) v1 = counts[base + 1];
        if (base + 2 < n) v2 = counts[base + 2];
        if (base + 3 < n) v3 = counts[base + 3];
    }
    int s = v0 + v1 + v2 + v3;
    sdata[t] = s;
    __syncthreads();
    for (int off = 1; off < SCAN_B; off <<= 1) {
        int x = (t >= off) ? sdata[t - off] : 0;
        __syncthreads();
        sdata[t] += x;
        __syncthreads();
    }
    int excl = sdata[t] - s;
    if (t == SCAN_B - 1) blockSums[blockIdx.x] = sdata[t];
    if (base     < n) row_ptr[base]     = excl;
    if (base + 1 < n) row_ptr[base + 1] = excl + v0;
    if (base + 2 < n) row_ptr[base + 2] = excl + v0 + v1;
    if (base + 3 < n) row_ptr[base + 3] = excl + v0 + v1 + v2;
}

__global__ void scan2_kernel(int* __restrict__ blockSums, int G) {
    if (threadIdx.x == 0 && blockIdx.x == 0) {
        int run = 0;
        for (int i = 0; i < G; ++i) { int v = blockSums[i]; blockSums[i] = run; run += v; }
    }
}

__global__ void scan3_kernel(int* __restrict__ row_ptr,
                             const int* __restrict__ blockSums,
                             int* __restrict__ cursor, int n, int e) {
    int i = blockIdx.x * blockDim.x + threadIdx.x;
    if (i < n) {
        int v = row_ptr[i] + blockSums[i >> 10];
        row_ptr[i] = v;
        cursor[i] = v;
    }
    if (i == 0) row_ptr[n] = e;
}

__global__ void build_kernel(const int* __restrict__ src,
                             const int* __restrict__ dst,
                             const float* __restrict__ ew,
                             const float* __restrict__ dis,
                             int* __restrict__ cursor,
                             int2* __restrict__ pairs, int e) {
    int i = blockIdx.x * blockDim.x + threadIdx.x;
    if (i < e) {
        int s = src[i], c = dst[i];
        float nm = dis[s] * ew[i] * dis[c];
        int pos = atomicAdd(&cursor[c], 1);
        pairs[pos] = make_int2(s, __float_as_int(nm));
    }
}

__global__ void agg_kernel(const int* __restrict__ row_ptr,
                           const int2* __restrict__ pairs,
                           const float* __restrict__ h,
                           const float* __restrict__ dis,
                           const float* __restrict__ b,
                           float* __restrict__ out, int n) {
    int t = threadIdx.x;
    int node = blockIdx.x * 4 + (t >> 6);
    int d = t & 63;
    if (node >= n) return;

    float s0 = dis[node];
    float acc = b[d] + s0 * s0 * h[(size_t)node * D + d];

    int beg = row_ptr[node], end = row_ptr[node + 1];
    #pragma unroll 4
    for (int ee = beg; ee < end; ++ee) {
        int2 p = pairs[ee];
        acc = fmaf(__int_as_float(p.y), h[(size_t)p.x * D + d], acc);
    }
    out[(size_t)node * D + d] = acc;
}

// ===========================================================================
extern "C" void kernel_launch(void* const* d_in, const int* in_sizes, int n_in,
                              void* d_out, int out_size, void* d_ws, size_t ws_size,
                              hipStream_t stream) {
    const float* x  = (const float*)d_in[0];
    const float* ea = (const float*)d_in[1];
    const float* W1 = (const float*)d_in[2];
    const float* b1 = (const float*)d_in[3];
    const float* W2 = (const float*)d_in[4];
    const float* b2 = (const float*)d_in[5];
    const int*   ei = (const int*)d_in[6];

    const int n = in_sizes[0] / D;      // 100000
    const int e = in_sizes[1];          // 1200000
    const int* src = ei;
    const int* dst = ei + e;
    float* out = (float*)d_out;

    const int B = 256;
    dim3 blk(B);
    dim3 pblk(PTH);
    int gN = (n + B - 1) / B;
    int gE = (e + B - 1) / B;
    int gL   = (n + 3) / 4;             // agg: 4 nodes/block
    int gL32 = (n + 31) / 32;           // linear: 32 nodes/block
    int nchunk  = (e + CHUNK - 1) / CHUNK;
    int nb_used = (n + BSIZE - 1) / BSIZE;

    // ---- partition-path workspace layout (word offsets, 256-word aligned) --
    size_t o = 0;
    auto alloc = [&](size_t words) { size_t r = o; o = (o + words + 255) & ~(size_t)255; return r; };
    size_t off_hist  = alloc((size_t)NBUCKET * nchunk);
    size_t off_ofs   = alloc((size_t)NBUCKET * nchunk);
    size_t off_btot  = alloc(NBUCKET);
    size_t off_bbase = alloc(NBUCKET + 1);
    size_t off_psw   = alloc((size_t)e * 2);
    size_t off_pairs = alloc((size_t)e * 2);
    size_t off_rp    = alloc(n + 1);
    size_t off_dis   = alloc(n);
    size_t off_h1    = alloc((size_t)n * D / 2);   // __half
    size_t off_o1    = alloc((size_t)n * D / 2);   // __half
    size_t need_bytes = o * 4;

    float* ws = (float*)d_ws;

    if (ws_size >= need_bytes && n <= NBUCKET * BSIZE) {
        // ================= PARTITION PATH =================
        int*    hist  = (int*)(ws + off_hist);
        int*    ofs   = (int*)(ws + off_ofs);
        int*    btot  = (int*)(ws + off_btot);
        int*    bbase = (int*)(ws + off_bbase);
        int2*   psw   = (int2*)(ws + off_psw);
        int2*   pairs = (int2*)(ws + off_pairs);
        int*    rp    = (int*)(ws + off_rp);
        float*  dis   = ws + off_dis;
        __half* h1    = (__half*)(ws + off_h1);
        __half* o1    = (__half*)(ws + off_o1);

        part_hist_kernel<<<nchunk, pblk, 0, stream>>>(dst, e, nchunk, hist);
        part_scanA_kernel<<<NBUCKET, blk, 0, stream>>>(hist, nchunk, ofs, btot);
        part_scanB_kernel<<<1, dim3(NBUCKET), 0, stream>>>(btot, bbase, e);
        part_scatter_kernel<<<nchunk, pblk, 0, stream>>>(src, dst, ea, ofs, bbase, nchunk, e, psw);
        bucket_bin_kernel<<<nb_used, pblk, 0, stream>>>(psw, bbase, n, e, pairs, rp, dis);

        // h1' = dis * (x @ W1^T)
        linear_kernel<false, true, float, __half><<<gL32, blk, 0, stream>>>(x, W1, dis, h1, n);
        // o1 = relu(b1 + dis * T1)
        agg_csr_kernel<true, __half><<<gL, blk, 0, stream>>>(rp, pairs, h1, dis, b1, o1, n);
        // h2' = dis * (o1 @ W2^T)   (reuse h1 buffer)
        linear_kernel<false, true, __half, __half><<<gL32, blk, 0, stream>>>(o1, W2, dis, h1, n);
        // out = b2 + dis * T2
        agg_csr_kernel<false, float><<<gL, blk, 0, stream>>>(rp, pairs, h1, dis, b2, out, n);
    } else {
        // ================= CSR FALLBACK (proven R2, fp32) =================
        size_t o2 = 0;
        auto alloc2 = [&](size_t words) { size_t r = o2; o2 = (o2 + words + 255) & ~(size_t)255; return r; };
        float* dis       = ws + alloc2(n);
        int*   row_ptr   = (int*)(ws + alloc2(n + 1));
        int*   cursor    = (int*)(ws + alloc2(n));
        int*   blockSums = (int*)(ws + alloc2(512));
        int2*  pairs     = (int2*)(ws + alloc2((size_t)e * 2));
        float* h         = ws + alloc2((size_t)n * D);
        float* out1      = ws + alloc2((size_t)n * D);
        int*   counts    = cursor;
        int G = (n + SCAN_TILE - 1) / SCAN_TILE;

        init_deg_counts_kernel<<<gN, blk, 0, stream>>>(dis, counts, n);
        edge_hist_kernel<<<gE, blk, 0, stream>>>(dst, ea, dis, counts, e);
        finish_dis_kernel<<<gN, blk, 0, stream>>>(dis, n);
        scan1_kernel<<<G, blk, 0, stream>>>(counts, n, row_ptr, blockSums);
        scan2_kernel<<<1, blk, 0, stream>>>(blockSums, G);
        scan3_kernel<<<gN, blk, 0, stream>>>(row_ptr, blockSums, cursor, n, e);
        build_kernel<<<gE, blk, 0, stream>>>(src, dst, ea, dis, cursor, pairs, e);

        linear_kernel<false, false, float, float><<<gL32, blk, 0, stream>>>(x, W1, nullptr, h, n);
        agg_kernel<<<gL, blk, 0, stream>>>(row_ptr, pairs, h, dis, b1, out1, n);

        linear_kernel<true, false, float, float><<<gL32, blk, 0, stream>>>(out1, W2, nullptr, h, n);
        agg_kernel<<<gL, blk, 0, stream>>>(row_ptr, pairs, h, dis, b2, out, n);
    }
}